// Round 1
// baseline (1726.075 us; speedup 1.0000x reference)
//
#include <hip/hip_runtime.h>
#include <hip/hip_bf16.h>

#define NN 20000
#define TT 512
#define LL 256
#define HIDC 512
#define HH 4
#define DD 64
#define EE 320000

// ---------------- degree / CSR build ----------------
__global__ void deg_kernel(const int* __restrict__ src, const int* __restrict__ dst,
                           int* deg_in, int* deg_tot) {
    int e = blockIdx.x * blockDim.x + threadIdx.x;
    if (e >= EE) return;
    atomicAdd(&deg_in[dst[e]], 1);
    atomicAdd(&deg_tot[src[e]], 1);
    atomicAdd(&deg_tot[dst[e]], 1);
}

__global__ void scan_kernel(const int* __restrict__ deg, int* row_start, int n) {
    __shared__ int sm[1024];
    __shared__ int s_carry;
    int tid = threadIdx.x;
    if (tid == 0) s_carry = 0;
    __syncthreads();
    for (int base = 0; base < n; base += 1024) {
        int i = base + tid;
        int v = (i < n) ? deg[i] : 0;
        sm[tid] = v;
        __syncthreads();
        for (int off = 1; off < 1024; off <<= 1) {
            int t = (tid >= off) ? sm[tid - off] : 0;
            __syncthreads();
            sm[tid] += t;
            __syncthreads();
        }
        int incl = sm[tid];
        int carry = s_carry;
        if (i < n) row_start[i] = carry + incl - v;
        __syncthreads();
        if (tid == 1023) s_carry = carry + sm[1023];
        __syncthreads();
    }
    if (tid == 0) row_start[n] = s_carry;
}

__global__ void fill_csr_kernel(const int* __restrict__ dst, const int* __restrict__ row_start,
                                int* cursor, int* csr) {
    int e = blockIdx.x * blockDim.x + threadIdx.x;
    if (e >= EE) return;
    int d = dst[e];
    int p = atomicAdd(&cursor[d], 1);
    csr[row_start[d] + p] = e;
}

// ---------------- z = x + segment_sum(x[src] -> dst), F = 512 ----------------
__global__ void agg_add_kernel(const float* __restrict__ X, float* __restrict__ Z,
                               const int* __restrict__ csr, const int* __restrict__ row_start,
                               const int* __restrict__ src) {
    __shared__ int s_src[256];
    int node = blockIdx.x;
    int tid = threadIdx.x;
    int c0 = tid, c1 = tid + 256;
    int start = row_start[node], end = row_start[node + 1];
    float a0 = X[(size_t)node * 512 + c0];
    float a1 = X[(size_t)node * 512 + c1];
    for (int k0 = start; k0 < end; k0 += 256) {
        int k = k0 + tid;
        if (k < end) s_src[tid] = src[csr[k]];
        __syncthreads();
        int cnt = min(256, end - k0);
        for (int j = 0; j < cnt; j++) {
            const float* row = X + (size_t)s_src[j] * 512;
            a0 += row[c0];
            a1 += row[c1];
        }
        __syncthreads();
    }
    Z[(size_t)node * 512 + c0] = a0;
    Z[(size_t)node * 512 + c1] = a1;
}

// ---------------- fp32 tiled GEMM: C = [relu](A[M,K] @ W[K,N] + bias) ----------------
template <int RELU>
__global__ void gemm_kernel(const float* __restrict__ A, const float* __restrict__ W,
                            const float* __restrict__ bias, float* __restrict__ C,
                            int M, int K, int Nn) {
    __shared__ float As[64][17];
    __shared__ float Bs[16][65];
    int tid = threadIdx.x;
    int bm = blockIdx.y * 64, bn = blockIdx.x * 64;
    int tx = tid % 16, ty = tid / 16;
    float acc[4][4] = {};
    for (int k0 = 0; k0 < K; k0 += 16) {
#pragma unroll
        for (int p = 0; p < 4; p++) {
            int r = p * 16 + tid / 16;
            int c = tid % 16;
            int gr = bm + r;
            As[r][c] = (gr < M) ? A[(size_t)gr * K + k0 + c] : 0.f;
        }
#pragma unroll
        for (int p = 0; p < 4; p++) {
            int rr = p * 4 + tid / 64;
            int cc = tid % 64;
            Bs[rr][cc] = W[(size_t)(k0 + rr) * Nn + bn + cc];
        }
        __syncthreads();
#pragma unroll
        for (int kk = 0; kk < 16; kk++) {
            float a[4], b[4];
#pragma unroll
            for (int i = 0; i < 4; i++) a[i] = As[ty * 4 + i][kk];
#pragma unroll
            for (int j = 0; j < 4; j++) b[j] = Bs[kk][tx * 4 + j];
#pragma unroll
            for (int i = 0; i < 4; i++)
#pragma unroll
                for (int j = 0; j < 4; j++) acc[i][j] += a[i] * b[j];
        }
        __syncthreads();
    }
#pragma unroll
    for (int i = 0; i < 4; i++) {
        int gr = bm + ty * 4 + i;
        if (gr >= M) continue;
#pragma unroll
        for (int j = 0; j < 4; j++) {
            int gc = bn + tx * 4 + j;
            float v = acc[i][j] + (bias ? bias[gc] : 0.f);
            if (RELU) v = fmaxf(v, 0.f);
            C[(size_t)gr * Nn + gc] = v;
        }
    }
}

// ---------------- BatchNorm (training stats, biased var) ----------------
__global__ void bn_stats_kernel(const float* __restrict__ h, float* cs, float* csq) {
    int col = threadIdx.x;  // 256
    int r0 = blockIdx.x * 100;
    int r1 = min(r0 + 100, NN);
    float s = 0.f, sq = 0.f;
    for (int r = r0; r < r1; r++) {
        float v = h[(size_t)r * 256 + col];
        s += v;
        sq += v * v;
    }
    atomicAdd(&cs[col], s);
    atomicAdd(&csq[col], sq);
}

__global__ void bn_apply_kernel(float* __restrict__ h, const float* __restrict__ cs,
                                const float* __restrict__ csq, const float* __restrict__ g,
                                const float* __restrict__ b) {
    size_t i = (size_t)blockIdx.x * blockDim.x + threadIdx.x;
    if (i >= (size_t)NN * 256) return;
    int col = (int)(i & 255);
    float mu = cs[col] * (1.f / NN);
    float var = csq[col] * (1.f / NN) - mu * mu;
    float inv = rsqrtf(var + 1e-5f);
    h[i] = (h[i] - mu) * inv * g[col] + b[col];
}

// ---------------- GATv2 edge logits ----------------
__global__ void edge_logit_kernel(const float* __restrict__ xl, const float* __restrict__ xr,
                                  const int* __restrict__ src, const int* __restrict__ dst,
                                  const float* __restrict__ att, float* __restrict__ elog) {
    int lane = threadIdx.x & 63;
    int wave = threadIdx.x >> 6;
    int e = blockIdx.x * 4 + wave;
    if (e >= EE) return;
    int s = src[e], t = dst[e];
#pragma unroll
    for (int h = 0; h < 4; h++) {
        float v = xl[(size_t)s * 256 + h * 64 + lane] + xr[(size_t)t * 256 + h * 64 + lane];
        v = v > 0.f ? v : 0.2f * v;
        v *= att[h * 64 + lane];
#pragma unroll
        for (int o = 32; o > 0; o >>= 1) v += __shfl_xor(v, o);
        if (lane == 0) elog[(size_t)e * 4 + h] = v;
    }
}

// ---------------- per-dst softmax over in-edges (in-place elog -> alpha) ----------------
__global__ void edge_softmax_kernel(float* __restrict__ ea, const int* __restrict__ csr,
                                    const int* __restrict__ row_start) {
    int lane = threadIdx.x & 63;
    int wave = threadIdx.x >> 6;
    int node = blockIdx.x * 4 + wave;
    if (node >= NN) return;
    int start = row_start[node], end = row_start[node + 1];
    if (start == end) return;
    for (int h = 0; h < 4; h++) {
        float m = -1e30f;
        for (int k = start + lane; k < end; k += 64) m = fmaxf(m, ea[(size_t)csr[k] * 4 + h]);
#pragma unroll
        for (int o = 32; o > 0; o >>= 1) m = fmaxf(m, __shfl_xor(m, o));
        float ssum = 0.f;
        for (int k = start + lane; k < end; k += 64) ssum += __expf(ea[(size_t)csr[k] * 4 + h] - m);
#pragma unroll
        for (int o = 32; o > 0; o >>= 1) ssum += __shfl_xor(ssum, o);
        float rinv = 1.f / ssum;
        for (int k = start + lane; k < end; k += 64) {
            size_t idx = (size_t)csr[k] * 4 + h;
            ea[idx] = __expf(ea[idx] - m) * rinv;
        }
    }
}

// ---------------- gat_out = segsum(alpha * xl[src]) + gat_b ----------------
__global__ void gat_out_kernel(const float* __restrict__ alpha, const float* __restrict__ xl,
                               const int* __restrict__ csr, const int* __restrict__ row_start,
                               const int* __restrict__ src, const float* __restrict__ gat_b,
                               float* __restrict__ out) {
    __shared__ int s_src[256];
    __shared__ float s_al[256 * 4];
    int node = blockIdx.x;
    int tid = threadIdx.x;
    int start = row_start[node], end = row_start[node + 1];
    int head = tid >> 6;
    float acc = 0.f;
    for (int k0 = start; k0 < end; k0 += 256) {
        int k = k0 + tid;
        if (k < end) {
            int e = csr[k];
            s_src[tid] = src[e];
            float4 a4 = ((const float4*)alpha)[e];
            ((float4*)s_al)[tid] = a4;
        }
        __syncthreads();
        int cnt = min(256, end - k0);
        for (int j = 0; j < cnt; j++) {
            acc += s_al[j * 4 + head] * xl[(size_t)s_src[j] * 256 + tid];
        }
        __syncthreads();
    }
    out[(size_t)node * 256 + tid] = acc + gat_b[tid];
}

// ---------------- node_att accumulation + edge output ----------------
// edge_w[h][e] == alpha_flat[h*E + e] (reshape is flat reinterpretation)
__global__ void node_att_kernel(const float* __restrict__ alpha, const int* __restrict__ src,
                                const int* __restrict__ dst, float* __restrict__ na,
                                float* __restrict__ out_edge) {
    int e = blockIdx.x * blockDim.x + threadIdx.x;
    if (e >= EE) return;
    int s = src[e], t = dst[e];
    float tot = 0.f;
#pragma unroll
    for (int h = 0; h < 4; h++) {
        float v = alpha[(size_t)h * EE + e];
        tot += v;
        atomicAdd(&na[h * NN + s], v);
        atomicAdd(&na[h * NN + t], v);
    }
    out_edge[e] = 0.25f * tot;
}

__global__ void head_stats_kernel(const float* __restrict__ na, const int* __restrict__ deg_tot,
                                  float* hm, float* hs) {
    __shared__ float red[1024];
    int h = blockIdx.x;
    int tid = threadIdx.x;
    float m = -1e30f;
    for (int i = tid; i < NN; i += 1024) {
        float v = na[h * NN + i] / ((float)deg_tot[i] + 1e-9f);
        m = fmaxf(m, v);
    }
    red[tid] = m;
    __syncthreads();
    for (int o = 512; o > 0; o >>= 1) {
        if (tid < o) red[tid] = fmaxf(red[tid], red[tid + o]);
        __syncthreads();
    }
    m = red[0];
    __syncthreads();
    float s = 0.f;
    for (int i = tid; i < NN; i += 1024) {
        float v = na[h * NN + i] / ((float)deg_tot[i] + 1e-9f);
        s += __expf(v - m);
    }
    red[tid] = s;
    __syncthreads();
    for (int o = 512; o > 0; o >>= 1) {
        if (tid < o) red[tid] += red[tid + o];
        __syncthreads();
    }
    if (tid == 0) {
        hm[h] = m;
        hs[h] = red[0];
    }
}

__global__ void node_out_kernel(const float* __restrict__ na, const int* __restrict__ deg_tot,
                                const float* __restrict__ hm, const float* __restrict__ hs,
                                float* __restrict__ out_node) {
    int i = blockIdx.x * blockDim.x + threadIdx.x;
    if (i >= NN) return;
    float acc = 0.f;
#pragma unroll
    for (int h = 0; h < 4; h++) {
        float v = na[h * NN + i] / ((float)deg_tot[i] + 1e-9f);
        acc += __expf(v - hm[h]) / hs[h];
    }
    out_node[i] = 0.25f * acc;
}

// ---------------- LayerNorm(N*L) + Linear + sigmoid ----------------
__global__ void ln_stats_kernel(const float* __restrict__ x, float* scal) {
    __shared__ float rs[256], rq[256];
    const size_t total = (size_t)NN * 256;
    float s = 0.f, q = 0.f;
    for (size_t i = (size_t)blockIdx.x * blockDim.x + threadIdx.x; i < total;
         i += (size_t)gridDim.x * blockDim.x) {
        float v = x[i];
        s += v;
        q += v * v;
    }
    rs[threadIdx.x] = s;
    rq[threadIdx.x] = q;
    __syncthreads();
    for (int o = 128; o > 0; o >>= 1) {
        if (threadIdx.x < o) {
            rs[threadIdx.x] += rs[threadIdx.x + o];
            rq[threadIdx.x] += rq[threadIdx.x + o];
        }
        __syncthreads();
    }
    if (threadIdx.x == 0) {
        atomicAdd(&scal[0], rs[0]);
        atomicAdd(&scal[1], rq[0]);
    }
}

__global__ void ln_dot_kernel(const float* __restrict__ x, const float* __restrict__ g,
                              const float* __restrict__ b, const float* __restrict__ Wp,
                              float* scal) {
    __shared__ float rs[256];
    const size_t total = (size_t)NN * 256;
    float mu = scal[0] / (float)total;
    float var = scal[1] / (float)total - mu * mu;
    float inv = rsqrtf(var + 1e-5f);
    float s = 0.f;
    for (size_t i = (size_t)blockIdx.x * blockDim.x + threadIdx.x; i < total;
         i += (size_t)gridDim.x * blockDim.x) {
        float v = (x[i] - mu) * inv * g[i] + b[i];
        s += v * Wp[i];
    }
    rs[threadIdx.x] = s;
    __syncthreads();
    for (int o = 128; o > 0; o >>= 1) {
        if (threadIdx.x < o) rs[threadIdx.x] += rs[threadIdx.x + o];
        __syncthreads();
    }
    if (threadIdx.x == 0) atomicAdd(&scal[2], rs[0]);
}

__global__ void finalize_kernel(const float* __restrict__ scal, const float* __restrict__ bp,
                                float* __restrict__ out) {
    float z = scal[2] + bp[0];
    out[0] = 1.f / (1.f + __expf(-z));
}

extern "C" void kernel_launch(void* const* d_in, const int* in_sizes, int n_in,
                              void* d_out, int out_size, void* d_ws, size_t ws_size,
                              hipStream_t stream) {
    const float* x    = (const float*)d_in[0];
    const int* ei     = (const int*)d_in[1];
    const float* W1a  = (const float*)d_in[3];
    const float* b1a  = (const float*)d_in[4];
    const float* W1b  = (const float*)d_in[5];
    const float* b1b  = (const float*)d_in[6];
    const float* W2a  = (const float*)d_in[7];
    const float* b2a  = (const float*)d_in[8];
    const float* W2b  = (const float*)d_in[9];
    const float* b2b  = (const float*)d_in[10];
    const float* bn_g = (const float*)d_in[11];
    const float* bn_b = (const float*)d_in[12];
    const float* Wl   = (const float*)d_in[13];
    const float* Wr   = (const float*)d_in[14];
    const float* att  = (const float*)d_in[15];
    const float* gatb = (const float*)d_in[16];
    const float* ln_g = (const float*)d_in[17];
    const float* ln_b = (const float*)d_in[18];
    const float* Wp   = (const float*)d_in[19];
    const float* bp   = (const float*)d_in[20];

    const int* src = ei;
    const int* dst = ei + EE;

    float* out = (float*)d_out;
    float* out_pred = out;
    float* out_node = out + 1;
    float* out_edge = out + 1 + NN;

    // ---- workspace layout (floats) ----
    float* A     = (float*)d_ws;          // 20000*512
    float* Bb    = A + (size_t)NN * 512;  // 20000*512
    float* Cc    = Bb + (size_t)NN * 512; // 20000*256
    float* alpha = Cc + (size_t)NN * 256; // 320000*4
    float* na    = alpha + (size_t)EE * 4; // 4*20000
    float* csum  = na + 4 * NN;            // 256
    float* csq   = csum + 256;             // 256
    float* hm    = csq + 256;              // 4
    float* hs    = hm + 4;                 // 4
    float* scal  = hs + 4;                 // 8 (pad)
    int* deg_in    = (int*)(scal + 8);     // 20000
    int* deg_tot   = deg_in + NN;          // 20000
    int* row_start = deg_tot + NN;         // 20001
    int* cursor    = row_start + NN + 1;   // 20000
    int* csr       = cursor + NN;          // 320000

    // zero accumulators: na..scal (contiguous floats), deg_in..cursor (contiguous ints)
    hipMemsetAsync(na, 0, (size_t)(4 * NN + 256 + 256 + 4 + 4 + 8) * sizeof(float), stream);
    hipMemsetAsync(deg_in, 0, (size_t)(NN + NN + NN + 1 + NN) * sizeof(int), stream);

    const int EB = (EE + 255) / 256;  // 1250

    deg_kernel<<<EB, 256, 0, stream>>>(src, dst, deg_in, deg_tot);
    scan_kernel<<<1, 1024, 0, stream>>>(deg_in, row_start, NN);
    fill_csr_kernel<<<EB, 256, 0, stream>>>(dst, row_start, cursor, csr);

    // GIN layer 1
    agg_add_kernel<<<NN, 256, 0, stream>>>(x, A, csr, row_start, src);           // z1
    gemm_kernel<1><<<dim3(8, 313), 256, 0, stream>>>(A, W1a, b1a, Bb, NN, 512, 512);  // t1
    gemm_kernel<1><<<dim3(8, 313), 256, 0, stream>>>(Bb, W1b, b1b, A, NN, 512, 512);  // h1
    // GIN layer 2
    agg_add_kernel<<<NN, 256, 0, stream>>>(A, Bb, csr, row_start, src);          // z2
    gemm_kernel<1><<<dim3(4, 313), 256, 0, stream>>>(Bb, W2a, b2a, Cc, NN, 512, 256); // t2
    gemm_kernel<0><<<dim3(4, 313), 256, 0, stream>>>(Cc, W2b, b2b, A, NN, 256, 256); // h

    // BatchNorm
    bn_stats_kernel<<<200, 256, 0, stream>>>(A, csum, csq);
    bn_apply_kernel<<<(NN * 256 + 255) / 256, 256, 0, stream>>>(A, csum, csq, bn_g, bn_b);

    // GATv2 projections
    float* xl = Bb;
    float* xr = Bb + (size_t)NN * 256;
    gemm_kernel<0><<<dim3(4, 313), 256, 0, stream>>>(A, Wl, nullptr, xl, NN, 256, 256);
    gemm_kernel<0><<<dim3(4, 313), 256, 0, stream>>>(A, Wr, nullptr, xr, NN, 256, 256);

    edge_logit_kernel<<<EE / 4, 256, 0, stream>>>(xl, xr, src, dst, att, alpha);
    edge_softmax_kernel<<<NN / 4, 256, 0, stream>>>(alpha, csr, row_start);
    gat_out_kernel<<<NN, 256, 0, stream>>>(alpha, xl, csr, row_start, src, gatb, Cc);

    node_att_kernel<<<EB, 256, 0, stream>>>(alpha, src, dst, na, out_edge);
    head_stats_kernel<<<4, 1024, 0, stream>>>(na, deg_tot, hm, hs);
    node_out_kernel<<<(NN + 255) / 256, 256, 0, stream>>>(na, deg_tot, hm, hs, out_node);

    ln_stats_kernel<<<2560, 256, 0, stream>>>(Cc, scal);
    ln_dot_kernel<<<2560, 256, 0, stream>>>(Cc, ln_g, ln_b, Wp, scal);
    finalize_kernel<<<1, 1, 0, stream>>>(scal, bp, out_pred);
}

// Round 4
// 1029.633 us; speedup vs baseline: 1.6764x; 1.6764x over previous
//
#include <hip/hip_runtime.h>
#include <hip/hip_bf16.h>

#define NN 20000
#define TT 512
#define LL 256
#define HH 4
#define DD 64
#define EE 320000

typedef __attribute__((ext_vector_type(8))) short short8;
typedef __attribute__((ext_vector_type(4))) float f32x4;

__device__ __forceinline__ float bf2f(unsigned short u) {
    return __uint_as_float((unsigned)u << 16);
}
__device__ __forceinline__ unsigned short f2bf(float f) {
    __hip_bfloat16 h = __float2bfloat16(f);
    unsigned short r;
    __builtin_memcpy(&r, &h, 2);
    return r;
}

// ---------------- degree / CSR build ----------------
__global__ void deg_kernel(const int* __restrict__ src, const int* __restrict__ dst,
                           int* deg_in, int* deg_tot) {
    int e = blockIdx.x * blockDim.x + threadIdx.x;
    if (e >= EE) return;
    atomicAdd(&deg_in[dst[e]], 1);
    atomicAdd(&deg_tot[src[e]], 1);
    atomicAdd(&deg_tot[dst[e]], 1);
}

__global__ void scan_kernel(const int* __restrict__ deg, int* row_start, int n) {
    __shared__ int sm[1024];
    __shared__ int s_carry;
    int tid = threadIdx.x;
    if (tid == 0) s_carry = 0;
    __syncthreads();
    for (int base = 0; base < n; base += 1024) {
        int i = base + tid;
        int v = (i < n) ? deg[i] : 0;
        sm[tid] = v;
        __syncthreads();
        for (int off = 1; off < 1024; off <<= 1) {
            int t = (tid >= off) ? sm[tid - off] : 0;
            __syncthreads();
            sm[tid] += t;
            __syncthreads();
        }
        int incl = sm[tid];
        int carry = s_carry;
        if (i < n) row_start[i] = carry + incl - v;
        __syncthreads();
        if (tid == 1023) s_carry = carry + sm[1023];
        __syncthreads();
    }
    if (tid == 0) row_start[n] = s_carry;
}

__global__ void fill_csr_kernel(const int* __restrict__ dst, const int* __restrict__ row_start,
                                int* cursor, int* csr) {
    int e = blockIdx.x * blockDim.x + threadIdx.x;
    if (e >= EE) return;
    int d = dst[e];
    int p = atomicAdd(&cursor[d], 1);
    csr[row_start[d] + p] = e;
}

// ---------------- cast fp32 -> bf16 (vectorized) ----------------
__global__ void cast_bf_kernel(const float* __restrict__ in, unsigned short* __restrict__ out,
                               int n4) {
    int i = blockIdx.x * blockDim.x + threadIdx.x;
    if (i >= n4) return;
    float4 v = ((const float4*)in)[i];
    ushort4 o;
    o.x = f2bf(v.x); o.y = f2bf(v.y); o.z = f2bf(v.z); o.w = f2bf(v.w);
    ((ushort4*)out)[i] = o;
}

// ---------------- weight transpose + cast: W[K][N] fp32 -> Wt[N][K] bf16 ----------------
__global__ void wtrans_kernel(const float* __restrict__ W, unsigned short* __restrict__ Wt,
                              int K, int N) {
    __shared__ float t[32][33];
    int x = threadIdx.x & 31, y = threadIdx.x >> 5;  // 32 x 8
    int bn = blockIdx.x * 32, bk = blockIdx.y * 32;
#pragma unroll
    for (int i = 0; i < 32; i += 8) t[y + i][x] = W[(size_t)(bk + y + i) * N + bn + x];
    __syncthreads();
#pragma unroll
    for (int i = 0; i < 32; i += 8)
        Wt[(size_t)(bn + y + i) * K + bk + x] = f2bf(t[x][y + i]);
}

// ---------------- z = x + segment_sum(x[src] -> dst), bf16 in/out, F=512 ----------------
__global__ void agg_add_bf_kernel(const unsigned short* __restrict__ X,
                                  unsigned short* __restrict__ Z,
                                  const int* __restrict__ csr, const int* __restrict__ row_start,
                                  const int* __restrict__ src) {
    __shared__ int s_src[256];
    const int node = blockIdx.x, tid = threadIdx.x;
    const unsigned int* Xu = (const unsigned int*)X;
    const int start = row_start[node], end = row_start[node + 1];
    unsigned int self = Xu[(size_t)node * 256 + tid];
    float a0 = bf2f((unsigned short)(self & 0xffff));
    float a1 = bf2f((unsigned short)(self >> 16));
    for (int k0 = start; k0 < end; k0 += 256) {
        int k = k0 + tid;
        if (k < end) s_src[tid] = src[csr[k]];
        __syncthreads();
        int cnt = min(256, end - k0);
        for (int j = 0; j < cnt; ++j) {
            unsigned int v = Xu[(size_t)s_src[j] * 256 + tid];
            a0 += bf2f((unsigned short)(v & 0xffff));
            a1 += bf2f((unsigned short)(v >> 16));
        }
        __syncthreads();
    }
    ((unsigned int*)Z)[(size_t)node * 256 + tid] =
        (unsigned int)f2bf(a0) | ((unsigned int)f2bf(a1) << 16);
}

// ---------------- bf16 MFMA GEMM: C = [relu](A[M,K] @ Bt[N,K]^T + bias) ----------------
// 128x128 tile, BK=32, 4 waves (2x2), double-buffered LDS via global_load_lds width=16.
// LDS layout [khi][row][8] : linear in stage order, conflict-free ds_read_b128.
template <int RELU, int OUT_BF16>
__global__ __launch_bounds__(256)
void gemm_mfma_kernel(const unsigned short* __restrict__ A,
                      const unsigned short* __restrict__ Bt,
                      const float* __restrict__ bias, void* __restrict__ Cout,
                      int M, int K, int Nn) {
    __shared__ unsigned short lds[2][2][4][128][8];  // 32 KiB
    const int tid = threadIdx.x;
    const int wid = tid >> 6, lane = tid & 63;
    const int brow = blockIdx.y * 128, bcol = blockIdx.x * 128;
    const int wr = wid >> 1, wc = wid & 1;
    const int khi = lane >> 4, r15 = lane & 15;

    f32x4 acc[4][4] = {};

    // each wave stages 2 quarters of A and 2 of B per K-step
    const int q0 = wid * 2, q1 = wid * 2 + 1;
    const int kh0 = q0 >> 1, rh0 = q0 & 1;
    const int kh1 = q1 >> 1, rh1 = q1 & 1;
    int ar0 = brow + rh0 * 64 + lane; ar0 = ar0 < M ? ar0 : M - 1;
    int ar1 = brow + rh1 * 64 + lane; ar1 = ar1 < M ? ar1 : M - 1;
    const int bc0 = bcol + rh0 * 64 + lane;
    const int bc1 = bcol + rh1 * 64 + lane;
    const unsigned short* gA0 = A + (size_t)ar0 * K + kh0 * 8;
    const unsigned short* gA1 = A + (size_t)ar1 * K + kh1 * 8;
    const unsigned short* gB0 = Bt + (size_t)bc0 * K + kh0 * 8;
    const unsigned short* gB1 = Bt + (size_t)bc1 * K + kh1 * 8;

#define GLL(gp, lp) __builtin_amdgcn_global_load_lds( \
        (const __attribute__((address_space(1))) unsigned int*)(gp), \
        (__attribute__((address_space(3))) unsigned int*)(lp), 16, 0, 0)
#define STAGE(buf, kt) do { const int koff = (kt) * 32; \
        GLL(gA0 + koff, &lds[buf][0][kh0][rh0 * 64][0]); \
        GLL(gA1 + koff, &lds[buf][0][kh1][rh1 * 64][0]); \
        GLL(gB0 + koff, &lds[buf][1][kh0][rh0 * 64][0]); \
        GLL(gB1 + koff, &lds[buf][1][kh1][rh1 * 64][0]); \
    } while (0)

    const int NT = K >> 5;
    STAGE(0, 0);
    for (int kt = 0; kt < NT; ++kt) {
        const int cur = kt & 1;
        __syncthreads();  // drains vmcnt: buf[cur] staged; prev reads of buf[cur^1] done
        if (kt + 1 < NT) STAGE(cur ^ 1, kt + 1);
        short8 af[4], bfv[4];
#pragma unroll
        for (int m = 0; m < 4; ++m)
            af[m] = *(const short8*)&lds[cur][0][khi][wr * 64 + m * 16 + r15][0];
#pragma unroll
        for (int n = 0; n < 4; ++n)
            bfv[n] = *(const short8*)&lds[cur][1][khi][wc * 64 + n * 16 + r15][0];
#pragma unroll
        for (int m = 0; m < 4; ++m)
#pragma unroll
            for (int n = 0; n < 4; ++n)
                acc[m][n] =
                    __builtin_amdgcn_mfma_f32_16x16x32_bf16(af[m], bfv[n], acc[m][n], 0, 0, 0);
    }
#undef STAGE
#undef GLL

#pragma unroll
    for (int m = 0; m < 4; ++m) {
#pragma unroll
        for (int n = 0; n < 4; ++n) {
            const int col = bcol + wc * 64 + n * 16 + r15;
            const float bb = bias ? bias[col] : 0.f;
            f32x4 v = acc[m][n];
#pragma unroll
            for (int r = 0; r < 4; ++r) {
                const int row = brow + wr * 64 + m * 16 + khi * 4 + r;
                if (row < M) {
                    float o = v[r] + bb;
                    if (RELU) o = fmaxf(o, 0.f);
                    if (OUT_BF16)
                        ((unsigned short*)Cout)[(size_t)row * Nn + col] = f2bf(o);
                    else
                        ((float*)Cout)[(size_t)row * Nn + col] = o;
                }
            }
        }
    }
}

// ---------------- BatchNorm (training stats, biased var) ----------------
__global__ void bn_stats_kernel(const float* __restrict__ h, float* cs, float* csq) {
    int col = threadIdx.x;  // 256
    int r0 = blockIdx.x * 100;
    int r1 = min(r0 + 100, NN);
    float s = 0.f, sq = 0.f;
    for (int r = r0; r < r1; r++) {
        float v = h[(size_t)r * 256 + col];
        s += v;
        sq += v * v;
    }
    atomicAdd(&cs[col], s);
    atomicAdd(&csq[col], sq);
}

__global__ void bn_apply_bf_kernel(const float* __restrict__ h, const float* __restrict__ cs,
                                   const float* __restrict__ csq, const float* __restrict__ g,
                                   const float* __restrict__ b, unsigned short* __restrict__ out) {
    int i = blockIdx.x * blockDim.x + threadIdx.x;
    if (i >= NN * 256) return;
    int col = i & 255;
    float mu = cs[col] * (1.f / NN);
    float var = csq[col] * (1.f / NN) - mu * mu;
    float inv = rsqrtf(var + 1e-5f);
    out[i] = f2bf((h[i] - mu) * inv * g[col] + b[col]);
}

// ---------------- GATv2 edge logits (bf16 xl/xr) ----------------
__global__ void edge_logit_kernel(const unsigned short* __restrict__ xl,
                                  const unsigned short* __restrict__ xr,
                                  const int* __restrict__ src, const int* __restrict__ dst,
                                  const float* __restrict__ att, float* __restrict__ elog) {
    int lane = threadIdx.x & 63;
    int wave = threadIdx.x >> 6;
    int e = blockIdx.x * 4 + wave;
    if (e >= EE) return;
    int s = src[e], t = dst[e];
#pragma unroll
    for (int h = 0; h < 4; h++) {
        float v = bf2f(xl[(size_t)s * 256 + h * 64 + lane]) +
                  bf2f(xr[(size_t)t * 256 + h * 64 + lane]);
        v = v > 0.f ? v : 0.2f * v;
        v *= att[h * 64 + lane];
#pragma unroll
        for (int o = 32; o > 0; o >>= 1) v += __shfl_xor(v, o);
        if (lane == 0) elog[(size_t)e * 4 + h] = v;
    }
}

// ---------------- per-dst softmax over in-edges (in-place elog -> alpha) ----------------
__global__ void edge_softmax_kernel(float* __restrict__ ea, const int* __restrict__ csr,
                                    const int* __restrict__ row_start) {
    int lane = threadIdx.x & 63;
    int wave = threadIdx.x >> 6;
    int node = blockIdx.x * 4 + wave;
    if (node >= NN) return;
    int start = row_start[node], end = row_start[node + 1];
    if (start == end) return;
    for (int h = 0; h < 4; h++) {
        float m = -1e30f;
        for (int k = start + lane; k < end; k += 64) m = fmaxf(m, ea[(size_t)csr[k] * 4 + h]);
#pragma unroll
        for (int o = 32; o > 0; o >>= 1) m = fmaxf(m, __shfl_xor(m, o));
        float ssum = 0.f;
        for (int k = start + lane; k < end; k += 64) ssum += __expf(ea[(size_t)csr[k] * 4 + h] - m);
#pragma unroll
        for (int o = 32; o > 0; o >>= 1) ssum += __shfl_xor(ssum, o);
        float rinv = 1.f / ssum;
        for (int k = start + lane; k < end; k += 64) {
            size_t idx = (size_t)csr[k] * 4 + h;
            ea[idx] = __expf(ea[idx] - m) * rinv;
        }
    }
}

// ---------------- gat_out = segsum(alpha * xl[src]) + gat_b ----------------
__global__ void gat_out_kernel(const float* __restrict__ alpha,
                               const unsigned short* __restrict__ xl,
                               const int* __restrict__ csr, const int* __restrict__ row_start,
                               const int* __restrict__ src, const float* __restrict__ gat_b,
                               float* __restrict__ out) {
    __shared__ int s_src[256];
    __shared__ float s_al[256 * 4];
    int node = blockIdx.x;
    int tid = threadIdx.x;
    int start = row_start[node], end = row_start[node + 1];
    int head = tid >> 6;
    float acc = 0.f;
    for (int k0 = start; k0 < end; k0 += 256) {
        int k = k0 + tid;
        if (k < end) {
            int e = csr[k];
            s_src[tid] = src[e];
            float4 a4 = ((const float4*)alpha)[e];
            ((float4*)s_al)[tid] = a4;
        }
        __syncthreads();
        int cnt = min(256, end - k0);
        for (int j = 0; j < cnt; j++) {
            acc += s_al[j * 4 + head] * bf2f(xl[(size_t)s_src[j] * 256 + tid]);
        }
        __syncthreads();
    }
    out[(size_t)node * 256 + tid] = acc + gat_b[tid];
}

// ---------------- node_att accumulation + edge output ----------------
__global__ void node_att_kernel(const float* __restrict__ alpha, const int* __restrict__ src,
                                const int* __restrict__ dst, float* __restrict__ na,
                                float* __restrict__ out_edge) {
    int e = blockIdx.x * blockDim.x + threadIdx.x;
    if (e >= EE) return;
    int s = src[e], t = dst[e];
    float tot = 0.f;
#pragma unroll
    for (int h = 0; h < 4; h++) {
        float v = alpha[(size_t)h * EE + e];
        tot += v;
        atomicAdd(&na[h * NN + s], v);
        atomicAdd(&na[h * NN + t], v);
    }
    out_edge[e] = 0.25f * tot;
}

__global__ void head_stats_kernel(const float* __restrict__ na, const int* __restrict__ deg_tot,
                                  float* hm, float* hs) {
    __shared__ float red[1024];
    int h = blockIdx.x;
    int tid = threadIdx.x;
    float m = -1e30f;
    for (int i = tid; i < NN; i += 1024) {
        float v = na[h * NN + i] / ((float)deg_tot[i] + 1e-9f);
        m = fmaxf(m, v);
    }
    red[tid] = m;
    __syncthreads();
    for (int o = 512; o > 0; o >>= 1) {
        if (tid < o) red[tid] = fmaxf(red[tid], red[tid + o]);
        __syncthreads();
    }
    m = red[0];
    __syncthreads();
    float s = 0.f;
    for (int i = tid; i < NN; i += 1024) {
        float v = na[h * NN + i] / ((float)deg_tot[i] + 1e-9f);
        s += __expf(v - m);
    }
    red[tid] = s;
    __syncthreads();
    for (int o = 512; o > 0; o >>= 1) {
        if (tid < o) red[tid] += red[tid + o];
        __syncthreads();
    }
    if (tid == 0) {
        hm[h] = m;
        hs[h] = red[0];
    }
}

__global__ void node_out_kernel(const float* __restrict__ na, const int* __restrict__ deg_tot,
                                const float* __restrict__ hm, const float* __restrict__ hs,
                                float* __restrict__ out_node) {
    int i = blockIdx.x * blockDim.x + threadIdx.x;
    if (i >= NN) return;
    float acc = 0.f;
#pragma unroll
    for (int h = 0; h < 4; h++) {
        float v = na[h * NN + i] / ((float)deg_tot[i] + 1e-9f);
        acc += __expf(v - hm[h]) / hs[h];
    }
    out_node[i] = 0.25f * acc;
}

// ---------------- LayerNorm(N*L) + Linear + sigmoid ----------------
__global__ void ln_stats_kernel(const float* __restrict__ x, float* scal) {
    __shared__ float rs[256], rq[256];
    const size_t total = (size_t)NN * 256;
    float s = 0.f, q = 0.f;
    for (size_t i = (size_t)blockIdx.x * blockDim.x + threadIdx.x; i < total;
         i += (size_t)gridDim.x * blockDim.x) {
        float v = x[i];
        s += v;
        q += v * v;
    }
    rs[threadIdx.x] = s;
    rq[threadIdx.x] = q;
    __syncthreads();
    for (int o = 128; o > 0; o >>= 1) {
        if (threadIdx.x < o) {
            rs[threadIdx.x] += rs[threadIdx.x + o];
            rq[threadIdx.x] += rq[threadIdx.x + o];
        }
        __syncthreads();
    }
    if (threadIdx.x == 0) {
        atomicAdd(&scal[0], rs[0]);
        atomicAdd(&scal[1], rq[0]);
    }
}

__global__ void ln_dot_kernel(const float* __restrict__ x, const float* __restrict__ g,
                              const float* __restrict__ b, const float* __restrict__ Wp,
                              float* scal) {
    __shared__ float rs[256];
    const size_t total = (size_t)NN * 256;
    float mu = scal[0] / (float)total;
    float var = scal[1] / (float)total - mu * mu;
    float inv = rsqrtf(var + 1e-5f);
    float s = 0.f;
    for (size_t i = (size_t)blockIdx.x * blockDim.x + threadIdx.x; i < total;
         i += (size_t)gridDim.x * blockDim.x) {
        float v = (x[i] - mu) * inv * g[i] + b[i];
        s += v * Wp[i];
    }
    rs[threadIdx.x] = s;
    __syncthreads();
    for (int o = 128; o > 0; o >>= 1) {
        if (threadIdx.x < o) rs[threadIdx.x] += rs[threadIdx.x + o];
        __syncthreads();
    }
    if (threadIdx.x == 0) atomicAdd(&scal[2], rs[0]);
}

__global__ void finalize_kernel(const float* __restrict__ scal, const float* __restrict__ bp,
                                float* __restrict__ out) {
    float z = scal[2] + bp[0];
    out[0] = 1.f / (1.f + __expf(-z));
}

extern "C" void kernel_launch(void* const* d_in, const int* in_sizes, int n_in,
                              void* d_out, int out_size, void* d_ws, size_t ws_size,
                              hipStream_t stream) {
    const float* x    = (const float*)d_in[0];
    const int* ei     = (const int*)d_in[1];
    const float* W1a  = (const float*)d_in[3];
    const float* b1a  = (const float*)d_in[4];
    const float* W1b  = (const float*)d_in[5];
    const float* b1b  = (const float*)d_in[6];
    const float* W2a  = (const float*)d_in[7];
    const float* b2a  = (const float*)d_in[8];
    const float* W2b  = (const float*)d_in[9];
    const float* b2b  = (const float*)d_in[10];
    const float* bn_g = (const float*)d_in[11];
    const float* bn_b = (const float*)d_in[12];
    const float* Wl   = (const float*)d_in[13];
    const float* Wr   = (const float*)d_in[14];
    const float* att  = (const float*)d_in[15];
    const float* gatb = (const float*)d_in[16];
    const float* ln_g = (const float*)d_in[17];
    const float* ln_b = (const float*)d_in[18];
    const float* Wp   = (const float*)d_in[19];
    const float* bp   = (const float*)d_in[20];

    const int* src = ei;
    const int* dst = ei + EE;

    float* out = (float*)d_out;
    float* out_pred = out;
    float* out_node = out + 1;
    float* out_edge = out + 1 + NN;

    // ---- workspace layout ----
    // B0..B3: N*512 bf16 each (20.48 MB). Aliases (sequential, no overlap in time):
    //   B0: x_bf -> z2 -> h(fp32) -> gat_out(fp32)
    //   B1: z1 -> t2 -> xl(bf16)
    //   B2: t1 -> h_bn(bf16)
    //   B3: h1 -> xr(bf16)
    unsigned short* B0 = (unsigned short*)d_ws;
    unsigned short* B1 = B0 + (size_t)NN * 512;
    unsigned short* B2 = B1 + (size_t)NN * 512;
    unsigned short* B3 = B2 + (size_t)NN * 512;
    float* hbuf = (float*)B0;  // N*256 fp32 == N*512 bf16 bytes
    unsigned short* xl = B1;
    unsigned short* xr = B3;
    float* gout = (float*)B0;

    unsigned short* W1at = B3 + (size_t)NN * 512;
    unsigned short* W1bt = W1at + 512 * 512;
    unsigned short* W2at = W1bt + 512 * 512;
    unsigned short* W2bt = W2at + 256 * 512;
    unsigned short* Wlt  = W2bt + 256 * 256;
    unsigned short* Wrt  = Wlt + 256 * 256;
    float* alpha = (float*)(Wrt + 256 * 256);  // E*4 fp32, 16B-aligned
    float* na    = alpha + (size_t)EE * 4;     // 4*N
    float* csum  = na + 4 * NN;                // 256
    float* csq_  = csum + 256;                 // 256
    float* hm    = csq_ + 256;                 // 4
    float* hs    = hm + 4;                     // 4
    float* scal  = hs + 4;                     // 8
    int* deg_in    = (int*)(scal + 8);
    int* deg_tot   = deg_in + NN;
    int* row_start = deg_tot + NN;
    int* cursor    = row_start + NN + 1;
    int* csr       = cursor + NN;

    hipMemsetAsync(na, 0, (size_t)(4 * NN + 256 + 256 + 4 + 4 + 8) * sizeof(float), stream);
    hipMemsetAsync(deg_in, 0, (size_t)(NN + NN + NN + 1 + NN) * sizeof(int), stream);

    const int EB = (EE + 255) / 256;

    // weight prep (bf16, transposed to [N][K])
    wtrans_kernel<<<dim3(16, 16), 256, 0, stream>>>(W1a, W1at, 512, 512);
    wtrans_kernel<<<dim3(16, 16), 256, 0, stream>>>(W1b, W1bt, 512, 512);
    wtrans_kernel<<<dim3(8, 16), 256, 0, stream>>>(W2a, W2at, 512, 256);
    wtrans_kernel<<<dim3(8, 8), 256, 0, stream>>>(W2b, W2bt, 256, 256);
    wtrans_kernel<<<dim3(8, 8), 256, 0, stream>>>(Wl, Wlt, 256, 256);
    wtrans_kernel<<<dim3(8, 8), 256, 0, stream>>>(Wr, Wrt, 256, 256);

    cast_bf_kernel<<<(NN * 512 / 4 + 255) / 256, 256, 0, stream>>>(x, B0, NN * 512 / 4);

    deg_kernel<<<EB, 256, 0, stream>>>(src, dst, deg_in, deg_tot);
    scan_kernel<<<1, 1024, 0, stream>>>(deg_in, row_start, NN);
    fill_csr_kernel<<<EB, 256, 0, stream>>>(dst, row_start, cursor, csr);

    // GIN layer 1
    agg_add_bf_kernel<<<NN, 256, 0, stream>>>(B0, B1, csr, row_start, src);  // z1
    gemm_mfma_kernel<1, 1><<<dim3(4, 157), 256, 0, stream>>>(B1, W1at, b1a, B2, NN, 512, 512);
    gemm_mfma_kernel<1, 1><<<dim3(4, 157), 256, 0, stream>>>(B2, W1bt, b1b, B3, NN, 512, 512);
    // GIN layer 2
    agg_add_bf_kernel<<<NN, 256, 0, stream>>>(B3, B0, csr, row_start, src);  // z2
    gemm_mfma_kernel<1, 1><<<dim3(2, 157), 256, 0, stream>>>(B0, W2at, b2a, B1, NN, 512, 256);
    gemm_mfma_kernel<0, 0><<<dim3(2, 157), 256, 0, stream>>>(B1, W2bt, b2b, hbuf, NN, 256, 256);

    // BatchNorm -> bf16 h_bn in B2
    bn_stats_kernel<<<200, 256, 0, stream>>>(hbuf, csum, csq_);
    bn_apply_bf_kernel<<<(NN * 256 + 255) / 256, 256, 0, stream>>>(hbuf, csum, csq_, bn_g, bn_b,
                                                                   B2);

    // GATv2 projections (bf16 out)
    gemm_mfma_kernel<0, 1><<<dim3(2, 157), 256, 0, stream>>>(B2, Wlt, nullptr, xl, NN, 256, 256);
    gemm_mfma_kernel<0, 1><<<dim3(2, 157), 256, 0, stream>>>(B2, Wrt, nullptr, xr, NN, 256, 256);

    edge_logit_kernel<<<EE / 4, 256, 0, stream>>>(xl, xr, src, dst, att, alpha);
    edge_softmax_kernel<<<NN / 4, 256, 0, stream>>>(alpha, csr, row_start);
    gat_out_kernel<<<NN, 256, 0, stream>>>(alpha, xl, csr, row_start, src, gatb, gout);

    node_att_kernel<<<EB, 256, 0, stream>>>(alpha, src, dst, na, out_edge);
    head_stats_kernel<<<4, 1024, 0, stream>>>(na, deg_tot, hm, hs);
    node_out_kernel<<<(NN + 255) / 256, 256, 0, stream>>>(na, deg_tot, hm, hs, out_node);

    ln_stats_kernel<<<2560, 256, 0, stream>>>(gout, scal);
    ln_dot_kernel<<<2560, 256, 0, stream>>>(gout, ln_g, ln_b, Wp, scal);
    finalize_kernel<<<1, 1, 0, stream>>>(scal, bp, out_pred);
}

// Round 6
// 958.974 us; speedup vs baseline: 1.7999x; 1.0737x over previous
//
#include <hip/hip_runtime.h>
#include <hip/hip_bf16.h>

#define NN 20000
#define TT 512
#define LL 256
#define HH 4
#define DD 64
#define EE 320000

typedef __attribute__((ext_vector_type(8))) short short8;
typedef __attribute__((ext_vector_type(4))) float f32x4;

__device__ __forceinline__ float bf2f(unsigned short u) {
    return __uint_as_float((unsigned)u << 16);
}
__device__ __forceinline__ unsigned short f2bf(float f) {
    __hip_bfloat16 h = __float2bfloat16(f);
    unsigned short r;
    __builtin_memcpy(&r, &h, 2);
    return r;
}

// ---------------- degree / CSR build ----------------
__global__ void deg_kernel(const int* __restrict__ src, const int* __restrict__ dst,
                           int* deg_in, int* deg_tot) {
    int e = blockIdx.x * blockDim.x + threadIdx.x;
    if (e >= EE) return;
    atomicAdd(&deg_in[dst[e]], 1);
    atomicAdd(&deg_tot[src[e]], 1);
    atomicAdd(&deg_tot[dst[e]], 1);
}

__global__ void scan_kernel(const int* __restrict__ deg, int* row_start, int n) {
    __shared__ int sm[1024];
    __shared__ int s_carry;
    int tid = threadIdx.x;
    if (tid == 0) s_carry = 0;
    __syncthreads();
    for (int base = 0; base < n; base += 1024) {
        int i = base + tid;
        int v = (i < n) ? deg[i] : 0;
        sm[tid] = v;
        __syncthreads();
        for (int off = 1; off < 1024; off <<= 1) {
            int t = (tid >= off) ? sm[tid - off] : 0;
            __syncthreads();
            sm[tid] += t;
            __syncthreads();
        }
        int incl = sm[tid];
        int carry = s_carry;
        if (i < n) row_start[i] = carry + incl - v;
        __syncthreads();
        if (tid == 1023) s_carry = carry + sm[1023];
        __syncthreads();
    }
    if (tid == 0) row_start[n] = s_carry;
}

__global__ void fill_csr_kernel(const int* __restrict__ dst, const int* __restrict__ row_start,
                                int* cursor, int* csr) {
    int e = blockIdx.x * blockDim.x + threadIdx.x;
    if (e >= EE) return;
    int d = dst[e];
    int p = atomicAdd(&cursor[d], 1);
    csr[row_start[d] + p] = e;
}

// combined adjacency (both endpoints), 2E entries
__global__ void fill_adj2_kernel(const int* __restrict__ src, const int* __restrict__ dst,
                                 const int* __restrict__ rs2, int* cursor2, int* adj2) {
    int e = blockIdx.x * blockDim.x + threadIdx.x;
    if (e >= EE) return;
    int s = src[e];
    int p = atomicAdd(&cursor2[s], 1);
    adj2[rs2[s] + p] = e;
    int t = dst[e];
    int q = atomicAdd(&cursor2[t], 1);
    adj2[rs2[t] + q] = e;
}

// ---------------- cast fp32 -> bf16 (vectorized) ----------------
__global__ void cast_bf_kernel(const float* __restrict__ in, unsigned short* __restrict__ out,
                               int n4) {
    int i = blockIdx.x * blockDim.x + threadIdx.x;
    if (i >= n4) return;
    float4 v = ((const float4*)in)[i];
    ushort4 o;
    o.x = f2bf(v.x); o.y = f2bf(v.y); o.z = f2bf(v.z); o.w = f2bf(v.w);
    ((ushort4*)out)[i] = o;
}

// ---------------- weight transpose + cast: W[K][N] fp32 -> Wt[N][K] bf16 ----------------
__global__ void wtrans_kernel(const float* __restrict__ W, unsigned short* __restrict__ Wt,
                              int K, int N) {
    __shared__ float t[32][33];
    int x = threadIdx.x & 31, y = threadIdx.x >> 5;  // 32 x 8
    int bn = blockIdx.x * 32, bk = blockIdx.y * 32;
#pragma unroll
    for (int i = 0; i < 32; i += 8) t[y + i][x] = W[(size_t)(bk + y + i) * N + bn + x];
    __syncthreads();
#pragma unroll
    for (int i = 0; i < 32; i += 8)
        Wt[(size_t)(bn + y + i) * K + bk + x] = f2bf(t[x][y + i]);
}

// ---------------- z = x + segment_sum(x[src] -> dst), bf16 in/out, F=512 ----------------
__global__ void agg_add_bf_kernel(const unsigned short* __restrict__ X,
                                  unsigned short* __restrict__ Z,
                                  const int* __restrict__ csr, const int* __restrict__ row_start,
                                  const int* __restrict__ src) {
    __shared__ int s_src[256];
    const int node = blockIdx.x, tid = threadIdx.x;
    const unsigned int* Xu = (const unsigned int*)X;
    const int start = row_start[node], end = row_start[node + 1];
    unsigned int self = Xu[(size_t)node * 256 + tid];
    float a0 = bf2f((unsigned short)(self & 0xffff));
    float a1 = bf2f((unsigned short)(self >> 16));
    for (int k0 = start; k0 < end; k0 += 256) {
        int k = k0 + tid;
        if (k < end) s_src[tid] = src[csr[k]];
        __syncthreads();
        int cnt = min(256, end - k0);
        for (int j = 0; j < cnt; ++j) {
            unsigned int v = Xu[(size_t)s_src[j] * 256 + tid];
            a0 += bf2f((unsigned short)(v & 0xffff));
            a1 += bf2f((unsigned short)(v >> 16));
        }
        __syncthreads();
    }
    ((unsigned int*)Z)[(size_t)node * 256 + tid] =
        (unsigned int)f2bf(a0) | ((unsigned int)f2bf(a1) << 16);
}

// ---------------- bf16 MFMA GEMM: C = [relu](A[M,K] @ Bt[N,K]^T + bias) ----------------
// 128x128 tile, BK=32, 4 waves (2x2), double-buffered LDS via global_load_lds width=16.
// LDS layout [khi][row][8] : linear in stage order, conflict-free ds_read_b128.
template <int RELU, int OUT_BF16>
__global__ __launch_bounds__(256)
void gemm_mfma_kernel(const unsigned short* __restrict__ A,
                      const unsigned short* __restrict__ Bt,
                      const float* __restrict__ bias, void* __restrict__ Cout,
                      int M, int K, int Nn) {
    __shared__ unsigned short lds[2][2][4][128][8];  // 32 KiB
    const int tid = threadIdx.x;
    const int wid = tid >> 6, lane = tid & 63;
    const int brow = blockIdx.y * 128, bcol = blockIdx.x * 128;
    const int wr = wid >> 1, wc = wid & 1;
    const int khi = lane >> 4, r15 = lane & 15;

    f32x4 acc[4][4] = {};

    // each wave stages 2 quarters of A and 2 of B per K-step
    const int q0 = wid * 2, q1 = wid * 2 + 1;
    const int kh0 = q0 >> 1, rh0 = q0 & 1;
    const int kh1 = q1 >> 1, rh1 = q1 & 1;
    int ar0 = brow + rh0 * 64 + lane; ar0 = ar0 < M ? ar0 : M - 1;
    int ar1 = brow + rh1 * 64 + lane; ar1 = ar1 < M ? ar1 : M - 1;
    const int bc0 = bcol + rh0 * 64 + lane;
    const int bc1 = bcol + rh1 * 64 + lane;
    const unsigned short* gA0 = A + (size_t)ar0 * K + kh0 * 8;
    const unsigned short* gA1 = A + (size_t)ar1 * K + kh1 * 8;
    const unsigned short* gB0 = Bt + (size_t)bc0 * K + kh0 * 8;
    const unsigned short* gB1 = Bt + (size_t)bc1 * K + kh1 * 8;

#define GLL(gp, lp) __builtin_amdgcn_global_load_lds( \
        (const __attribute__((address_space(1))) unsigned int*)(gp), \
        (__attribute__((address_space(3))) unsigned int*)(lp), 16, 0, 0)
#define STAGE(buf, kt) do { const int koff = (kt) * 32; \
        GLL(gA0 + koff, &lds[buf][0][kh0][rh0 * 64][0]); \
        GLL(gA1 + koff, &lds[buf][0][kh1][rh1 * 64][0]); \
        GLL(gB0 + koff, &lds[buf][1][kh0][rh0 * 64][0]); \
        GLL(gB1 + koff, &lds[buf][1][kh1][rh1 * 64][0]); \
    } while (0)

    const int NT = K >> 5;
    STAGE(0, 0);
    for (int kt = 0; kt < NT; ++kt) {
        const int cur = kt & 1;
        __syncthreads();  // drains vmcnt: buf[cur] staged; prev reads of buf[cur^1] done
        if (kt + 1 < NT) STAGE(cur ^ 1, kt + 1);
        short8 af[4], bfv[4];
#pragma unroll
        for (int m = 0; m < 4; ++m)
            af[m] = *(const short8*)&lds[cur][0][khi][wr * 64 + m * 16 + r15][0];
#pragma unroll
        for (int n = 0; n < 4; ++n)
            bfv[n] = *(const short8*)&lds[cur][1][khi][wc * 64 + n * 16 + r15][0];
#pragma unroll
        for (int m = 0; m < 4; ++m)
#pragma unroll
            for (int n = 0; n < 4; ++n)
                acc[m][n] =
                    __builtin_amdgcn_mfma_f32_16x16x32_bf16(af[m], bfv[n], acc[m][n], 0, 0, 0);
    }
#undef STAGE
#undef GLL

#pragma unroll
    for (int m = 0; m < 4; ++m) {
#pragma unroll
        for (int n = 0; n < 4; ++n) {
            const int col = bcol + wc * 64 + n * 16 + r15;
            const float bb = bias ? bias[col] : 0.f;
            f32x4 v = acc[m][n];
#pragma unroll
            for (int r = 0; r < 4; ++r) {
                const int row = brow + wr * 64 + m * 16 + khi * 4 + r;
                if (row < M) {
                    float o = v[r] + bb;
                    if (RELU) o = fmaxf(o, 0.f);
                    if (OUT_BF16)
                        ((unsigned short*)Cout)[(size_t)row * Nn + col] = f2bf(o);
                    else
                        ((float*)Cout)[(size_t)row * Nn + col] = o;
                }
            }
        }
    }
}

// ---------------- BatchNorm (training stats, biased var) ----------------
__global__ void bn_stats_kernel(const float* __restrict__ h, float* cs, float* csq) {
    int col = threadIdx.x;  // 256
    int r0 = blockIdx.x * 100;
    int r1 = min(r0 + 100, NN);
    float s = 0.f, sq = 0.f;
    for (int r = r0; r < r1; r++) {
        float v = h[(size_t)r * 256 + col];
        s += v;
        sq += v * v;
    }
    atomicAdd(&cs[col], s);
    atomicAdd(&csq[col], sq);
}

__global__ void bn_apply_bf_kernel(const float* __restrict__ h, const float* __restrict__ cs,
                                   const float* __restrict__ csq, const float* __restrict__ g,
                                   const float* __restrict__ b, unsigned short* __restrict__ out) {
    int i = blockIdx.x * blockDim.x + threadIdx.x;
    if (i >= NN * 256) return;
    int col = i & 255;
    float mu = cs[col] * (1.f / NN);
    float var = csq[col] * (1.f / NN) - mu * mu;
    float inv = rsqrtf(var + 1e-5f);
    out[i] = f2bf((h[i] - mu) * inv * g[col] + b[col]);
}

// ---------------- GATv2 edge logits (bf16 xl/xr) ----------------
__global__ void edge_logit_kernel(const unsigned short* __restrict__ xl,
                                  const unsigned short* __restrict__ xr,
                                  const int* __restrict__ src, const int* __restrict__ dst,
                                  const float* __restrict__ att, float* __restrict__ elog) {
    int lane = threadIdx.x & 63;
    int wave = threadIdx.x >> 6;
    int e = blockIdx.x * 4 + wave;
    if (e >= EE) return;
    int s = src[e], t = dst[e];
#pragma unroll
    for (int h = 0; h < 4; h++) {
        float v = bf2f(xl[(size_t)s * 256 + h * 64 + lane]) +
                  bf2f(xr[(size_t)t * 256 + h * 64 + lane]);
        v = v > 0.f ? v : 0.2f * v;
        v *= att[h * 64 + lane];
#pragma unroll
        for (int o = 32; o > 0; o >>= 1) v += __shfl_xor(v, o);
        if (lane == 0) elog[(size_t)e * 4 + h] = v;
    }
}

// ---------------- per-dst softmax over in-edges, all 4 heads as float4 ----------------
__global__ void edge_softmax_kernel(float* __restrict__ ea, const int* __restrict__ csr,
                                    const int* __restrict__ row_start) {
    int lane = threadIdx.x & 63;
    int wave = threadIdx.x >> 6;
    int node = blockIdx.x * 4 + wave;
    if (node >= NN) return;
    int start = row_start[node], end = row_start[node + 1];
    if (start == end) return;
    float4* ea4 = (float4*)ea;
    float4 m = {-1e30f, -1e30f, -1e30f, -1e30f};
    for (int k = start + lane; k < end; k += 64) {
        float4 v = ea4[csr[k]];
        m.x = fmaxf(m.x, v.x); m.y = fmaxf(m.y, v.y);
        m.z = fmaxf(m.z, v.z); m.w = fmaxf(m.w, v.w);
    }
#pragma unroll
    for (int o = 32; o > 0; o >>= 1) {
        m.x = fmaxf(m.x, __shfl_xor(m.x, o));
        m.y = fmaxf(m.y, __shfl_xor(m.y, o));
        m.z = fmaxf(m.z, __shfl_xor(m.z, o));
        m.w = fmaxf(m.w, __shfl_xor(m.w, o));
    }
    float4 s = {0.f, 0.f, 0.f, 0.f};
    for (int k = start + lane; k < end; k += 64) {
        float4 v = ea4[csr[k]];
        s.x += __expf(v.x - m.x); s.y += __expf(v.y - m.y);
        s.z += __expf(v.z - m.z); s.w += __expf(v.w - m.w);
    }
#pragma unroll
    for (int o = 32; o > 0; o >>= 1) {
        s.x += __shfl_xor(s.x, o);
        s.y += __shfl_xor(s.y, o);
        s.z += __shfl_xor(s.z, o);
        s.w += __shfl_xor(s.w, o);
    }
    float4 rinv = {1.f / s.x, 1.f / s.y, 1.f / s.z, 1.f / s.w};
    for (int k = start + lane; k < end; k += 64) {
        int e = csr[k];
        float4 v = ea4[e];
        v.x = __expf(v.x - m.x) * rinv.x;
        v.y = __expf(v.y - m.y) * rinv.y;
        v.z = __expf(v.z - m.z) * rinv.z;
        v.w = __expf(v.w - m.w) * rinv.w;
        ea4[e] = v;
    }
}

// ---------------- gat_out = segsum(alpha * xl[src]) + gat_b ----------------
__global__ void gat_out_kernel(const float* __restrict__ alpha,
                               const unsigned short* __restrict__ xl,
                               const int* __restrict__ csr, const int* __restrict__ row_start,
                               const int* __restrict__ src, const float* __restrict__ gat_b,
                               float* __restrict__ out) {
    __shared__ int s_src[256];
    __shared__ float s_al[256 * 4];
    int node = blockIdx.x;
    int tid = threadIdx.x;
    int start = row_start[node], end = row_start[node + 1];
    int head = tid >> 6;
    float acc = 0.f;
    for (int k0 = start; k0 < end; k0 += 256) {
        int k = k0 + tid;
        if (k < end) {
            int e = csr[k];
            s_src[tid] = src[e];
            float4 a4 = ((const float4*)alpha)[e];
            ((float4*)s_al)[tid] = a4;
        }
        __syncthreads();
        int cnt = min(256, end - k0);
        for (int j = 0; j < cnt; j++) {
            acc += s_al[j * 4 + head] * bf2f(xl[(size_t)s_src[j] * 256 + tid]);
        }
        __syncthreads();
    }
    out[(size_t)node * 256 + tid] = acc + gat_b[tid];
}

// ---------------- node_att via combined-CSR gather (no atomics) ----------------
// edge_w[h][e] == abuf[h*E + e]  (flat reinterpretation of alpha [E,H])
__global__ void node_att_gather_kernel(const float* __restrict__ abuf,
                                       const int* __restrict__ adj2,
                                       const int* __restrict__ rs2, float* __restrict__ na) {
    int lane = threadIdx.x & 63;
    int wave = threadIdx.x >> 6;
    int node = blockIdx.x * 4 + wave;
    if (node >= NN) return;
    int start = rs2[node], end = rs2[node + 1];
    float s0 = 0.f, s1 = 0.f, s2 = 0.f, s3 = 0.f;
    for (int k = start + lane; k < end; k += 64) {
        int e = adj2[k];
        s0 += abuf[e];
        s1 += abuf[EE + e];
        s2 += abuf[2 * EE + e];
        s3 += abuf[3 * EE + e];
    }
#pragma unroll
    for (int o = 32; o > 0; o >>= 1) {
        s0 += __shfl_xor(s0, o);
        s1 += __shfl_xor(s1, o);
        s2 += __shfl_xor(s2, o);
        s3 += __shfl_xor(s3, o);
    }
    if (lane == 0) {
        na[node] = s0;
        na[NN + node] = s1;
        na[2 * NN + node] = s2;
        na[3 * NN + node] = s3;
    }
}

// ---------------- out_edge = mean over heads (coalesced) ----------------
__global__ void edge_mean_kernel(const float* __restrict__ abuf, float* __restrict__ out_edge) {
    int e = blockIdx.x * blockDim.x + threadIdx.x;
    if (e >= EE) return;
    out_edge[e] = 0.25f * (abuf[e] + abuf[EE + e] + abuf[2 * EE + e] + abuf[3 * EE + e]);
}

__global__ void head_stats_kernel(const float* __restrict__ na, const int* __restrict__ deg_tot,
                                  float* hm, float* hs) {
    __shared__ float red[1024];
    int h = blockIdx.x;
    int tid = threadIdx.x;
    float m = -1e30f;
    for (int i = tid; i < NN; i += 1024) {
        float v = na[h * NN + i] / ((float)deg_tot[i] + 1e-9f);
        m = fmaxf(m, v);
    }
    red[tid] = m;
    __syncthreads();
    for (int o = 512; o > 0; o >>= 1) {
        if (tid < o) red[tid] = fmaxf(red[tid], red[tid + o]);
        __syncthreads();
    }
    m = red[0];
    __syncthreads();
    float s = 0.f;
    for (int i = tid; i < NN; i += 1024) {
        float v = na[h * NN + i] / ((float)deg_tot[i] + 1e-9f);
        s += __expf(v - m);
    }
    red[tid] = s;
    __syncthreads();
    for (int o = 512; o > 0; o >>= 1) {
        if (tid < o) red[tid] += red[tid + o];
        __syncthreads();
    }
    if (tid == 0) {
        hm[h] = m;
        hs[h] = red[0];
    }
}

__global__ void node_out_kernel(const float* __restrict__ na, const int* __restrict__ deg_tot,
                                const float* __restrict__ hm, const float* __restrict__ hs,
                                float* __restrict__ out_node) {
    int i = blockIdx.x * blockDim.x + threadIdx.x;
    if (i >= NN) return;
    float acc = 0.f;
#pragma unroll
    for (int h = 0; h < 4; h++) {
        float v = na[h * NN + i] / ((float)deg_tot[i] + 1e-9f);
        acc += __expf(v - hm[h]) / hs[h];
    }
    out_node[i] = 0.25f * acc;
}

// ---------------- LayerNorm(N*L) + Linear + sigmoid ----------------
__global__ void ln_stats_kernel(const float* __restrict__ x, float* scal) {
    __shared__ float rs[256], rq[256];
    const size_t total = (size_t)NN * 256;
    float s = 0.f, q = 0.f;
    for (size_t i = (size_t)blockIdx.x * blockDim.x + threadIdx.x; i < total;
         i += (size_t)gridDim.x * blockDim.x) {
        float v = x[i];
        s += v;
        q += v * v;
    }
    rs[threadIdx.x] = s;
    rq[threadIdx.x] = q;
    __syncthreads();
    for (int o = 128; o > 0; o >>= 1) {
        if (threadIdx.x < o) {
            rs[threadIdx.x] += rs[threadIdx.x + o];
            rq[threadIdx.x] += rq[threadIdx.x + o];
        }
        __syncthreads();
    }
    if (threadIdx.x == 0) {
        atomicAdd(&scal[0], rs[0]);
        atomicAdd(&scal[1], rq[0]);
    }
}

__global__ void ln_dot_kernel(const float* __restrict__ x, const float* __restrict__ g,
                              const float* __restrict__ b, const float* __restrict__ Wp,
                              float* scal) {
    __shared__ float rs[256];
    const size_t total = (size_t)NN * 256;
    float mu = scal[0] / (float)total;
    float var = scal[1] / (float)total - mu * mu;
    float inv = rsqrtf(var + 1e-5f);
    float s = 0.f;
    for (size_t i = (size_t)blockIdx.x * blockDim.x + threadIdx.x; i < total;
         i += (size_t)gridDim.x * blockDim.x) {
        float v = (x[i] - mu) * inv * g[i] + b[i];
        s += v * Wp[i];
    }
    rs[threadIdx.x] = s;
    __syncthreads();
    for (int o = 128; o > 0; o >>= 1) {
        if (threadIdx.x < o) rs[threadIdx.x] += rs[threadIdx.x + o];
        __syncthreads();
    }
    if (threadIdx.x == 0) atomicAdd(&scal[2], rs[0]);
}

__global__ void finalize_kernel(const float* __restrict__ scal, const float* __restrict__ bp,
                                float* __restrict__ out) {
    float z = scal[2] + bp[0];
    out[0] = 1.f / (1.f + __expf(-z));
}

extern "C" void kernel_launch(void* const* d_in, const int* in_sizes, int n_in,
                              void* d_out, int out_size, void* d_ws, size_t ws_size,
                              hipStream_t stream) {
    const float* x    = (const float*)d_in[0];
    const int* ei     = (const int*)d_in[1];
    const float* W1a  = (const float*)d_in[3];
    const float* b1a  = (const float*)d_in[4];
    const float* W1b  = (const float*)d_in[5];
    const float* b1b  = (const float*)d_in[6];
    const float* W2a  = (const float*)d_in[7];
    const float* b2a  = (const float*)d_in[8];
    const float* W2b  = (const float*)d_in[9];
    const float* b2b  = (const float*)d_in[10];
    const float* bn_g = (const float*)d_in[11];
    const float* bn_b = (const float*)d_in[12];
    const float* Wl   = (const float*)d_in[13];
    const float* Wr   = (const float*)d_in[14];
    const float* att  = (const float*)d_in[15];
    const float* gatb = (const float*)d_in[16];
    const float* ln_g = (const float*)d_in[17];
    const float* ln_b = (const float*)d_in[18];
    const float* Wp   = (const float*)d_in[19];
    const float* bp   = (const float*)d_in[20];

    const int* src = ei;
    const int* dst = ei + EE;

    float* out = (float*)d_out;
    float* out_pred = out;
    float* out_node = out + 1;
    float* out_edge = out + 1 + NN;

    // ---- workspace layout ----
    unsigned short* B0 = (unsigned short*)d_ws;
    unsigned short* B1 = B0 + (size_t)NN * 512;
    unsigned short* B2 = B1 + (size_t)NN * 512;
    unsigned short* B3 = B2 + (size_t)NN * 512;
    float* hbuf = (float*)B0;  // N*256 fp32 == N*512 bf16 bytes
    unsigned short* xl = B1;
    unsigned short* xr = B3;
    float* gout = (float*)B0;

    unsigned short* W1at = B3 + (size_t)NN * 512;
    unsigned short* W1bt = W1at + 512 * 512;
    unsigned short* W2at = W1bt + 512 * 512;
    unsigned short* W2bt = W2at + 256 * 512;
    unsigned short* Wlt  = W2bt + 256 * 256;
    unsigned short* Wrt  = Wlt + 256 * 256;
    float* alpha = (float*)(Wrt + 256 * 256);  // E*4 fp32, 16B-aligned
    float* na    = alpha + (size_t)EE * 4;     // 4*N
    float* csum  = na + 4 * NN;                // 256
    float* csq_  = csum + 256;                 // 256
    float* hm    = csq_ + 256;                 // 4
    float* hs    = hm + 4;                     // 4
    float* scal  = hs + 4;                     // 8
    int* deg_in     = (int*)(scal + 8);        // N
    int* deg_tot    = deg_in + NN;             // N
    int* row_start  = deg_tot + NN;            // N+1
    int* row_start2 = row_start + NN + 1;      // N+1
    int* cursor     = row_start2 + NN + 1;     // N
    int* cursor2    = cursor + NN;             // N
    int* csr        = cursor2 + NN;            // E
    int* adj2       = csr + EE;                // 2E

    hipMemsetAsync(csum, 0, (size_t)(256 + 256 + 4 + 4 + 8) * sizeof(float), stream);
    hipMemsetAsync(deg_in, 0, (size_t)(6 * NN + 2) * sizeof(int), stream);

    const int EB = (EE + 255) / 256;

    // weight prep (bf16, transposed to [N][K])
    wtrans_kernel<<<dim3(16, 16), 256, 0, stream>>>(W1a, W1at, 512, 512);
    wtrans_kernel<<<dim3(16, 16), 256, 0, stream>>>(W1b, W1bt, 512, 512);
    wtrans_kernel<<<dim3(8, 16), 256, 0, stream>>>(W2a, W2at, 512, 256);
    wtrans_kernel<<<dim3(8, 8), 256, 0, stream>>>(W2b, W2bt, 256, 256);
    wtrans_kernel<<<dim3(8, 8), 256, 0, stream>>>(Wl, Wlt, 256, 256);
    wtrans_kernel<<<dim3(8, 8), 256, 0, stream>>>(Wr, Wrt, 256, 256);

    cast_bf_kernel<<<(NN * 512 / 4 + 255) / 256, 256, 0, stream>>>(x, B0, NN * 512 / 4);

    deg_kernel<<<EB, 256, 0, stream>>>(src, dst, deg_in, deg_tot);
    scan_kernel<<<1, 1024, 0, stream>>>(deg_in, row_start, NN);
    scan_kernel<<<1, 1024, 0, stream>>>(deg_tot, row_start2, NN);
    fill_csr_kernel<<<EB, 256, 0, stream>>>(dst, row_start, cursor, csr);
    fill_adj2_kernel<<<EB, 256, 0, stream>>>(src, dst, row_start2, cursor2, adj2);

    // GIN layer 1
    agg_add_bf_kernel<<<NN, 256, 0, stream>>>(B0, B1, csr, row_start, src);  // z1
    gemm_mfma_kernel<1, 1><<<dim3(4, 157), 256, 0, stream>>>(B1, W1at, b1a, B2, NN, 512, 512);
    gemm_mfma_kernel<1, 1><<<dim3(4, 157), 256, 0, stream>>>(B2, W1bt, b1b, B3, NN, 512, 512);
    // GIN layer 2
    agg_add_bf_kernel<<<NN, 256, 0, stream>>>(B3, B0, csr, row_start, src);  // z2
    gemm_mfma_kernel<1, 1><<<dim3(2, 157), 256, 0, stream>>>(B0, W2at, b2a, B1, NN, 512, 256);
    gemm_mfma_kernel<0, 0><<<dim3(2, 157), 256, 0, stream>>>(B1, W2bt, b2b, hbuf, NN, 256, 256);

    // BatchNorm -> bf16 h_bn in B2
    bn_stats_kernel<<<200, 256, 0, stream>>>(hbuf, csum, csq_);
    bn_apply_bf_kernel<<<(NN * 256 + 255) / 256, 256, 0, stream>>>(hbuf, csum, csq_, bn_g, bn_b,
                                                                   B2);

    // GATv2 projections (bf16 out)
    gemm_mfma_kernel<0, 1><<<dim3(2, 157), 256, 0, stream>>>(B2, Wlt, nullptr, xl, NN, 256, 256);
    gemm_mfma_kernel<0, 1><<<dim3(2, 157), 256, 0, stream>>>(B2, Wrt, nullptr, xr, NN, 256, 256);

    edge_logit_kernel<<<EE / 4, 256, 0, stream>>>(xl, xr, src, dst, att, alpha);
    edge_softmax_kernel<<<NN / 4, 256, 0, stream>>>(alpha, csr, row_start);
    gat_out_kernel<<<NN, 256, 0, stream>>>(alpha, xl, csr, row_start, src, gatb, gout);

    node_att_gather_kernel<<<NN / 4, 256, 0, stream>>>(alpha, adj2, row_start2, na);
    edge_mean_kernel<<<EB, 256, 0, stream>>>(alpha, out_edge);
    head_stats_kernel<<<4, 1024, 0, stream>>>(na, deg_tot, hm, hs);
    node_out_kernel<<<(NN + 255) / 256, 256, 0, stream>>>(na, deg_tot, hm, hs, out_node);

    ln_stats_kernel<<<2560, 256, 0, stream>>>(gout, scal);
    ln_dot_kernel<<<2560, 256, 0, stream>>>(gout, ln_g, ln_b, Wp, scal);
    finalize_kernel<<<1, 1, 0, stream>>>(scal, bp, out_pred);
}

// Round 8
// 830.752 us; speedup vs baseline: 2.0777x; 1.1543x over previous
//
#include <hip/hip_runtime.h>
#include <hip/hip_bf16.h>

#define NN 20000
#define TT 512
#define LL 256
#define HH 4
#define DD 64
#define EE 320000

typedef __attribute__((ext_vector_type(8))) short short8;
typedef __attribute__((ext_vector_type(4))) float f32x4;

__device__ __forceinline__ float bf2f(unsigned short u) {
    return __uint_as_float((unsigned)u << 16);
}
__device__ __forceinline__ unsigned short f2bf(float f) {
    __hip_bfloat16 h = __float2bfloat16(f);
    unsigned short r;
    __builtin_memcpy(&r, &h, 2);
    return r;
}

// ---------------- degree / CSR build ----------------
__global__ void deg_kernel(const int* __restrict__ src, const int* __restrict__ dst,
                           int* deg_in, int* deg_tot) {
    int e = blockIdx.x * blockDim.x + threadIdx.x;
    if (e >= EE) return;
    atomicAdd(&deg_in[dst[e]], 1);
    atomicAdd(&deg_tot[src[e]], 1);
    atomicAdd(&deg_tot[dst[e]], 1);
}

__global__ void scan_kernel(const int* __restrict__ deg, int* row_start, int n) {
    __shared__ int sm[1024];
    __shared__ int s_carry;
    int tid = threadIdx.x;
    if (tid == 0) s_carry = 0;
    __syncthreads();
    for (int base = 0; base < n; base += 1024) {
        int i = base + tid;
        int v = (i < n) ? deg[i] : 0;
        sm[tid] = v;
        __syncthreads();
        for (int off = 1; off < 1024; off <<= 1) {
            int t = (tid >= off) ? sm[tid - off] : 0;
            __syncthreads();
            sm[tid] += t;
            __syncthreads();
        }
        int incl = sm[tid];
        int carry = s_carry;
        if (i < n) row_start[i] = carry + incl - v;
        __syncthreads();
        if (tid == 1023) s_carry = carry + sm[1023];
        __syncthreads();
    }
    if (tid == 0) row_start[n] = s_carry;
}

__global__ void fill_csr_kernel(const int* __restrict__ dst, const int* __restrict__ row_start,
                                int* cursor, int* csr) {
    int e = blockIdx.x * blockDim.x + threadIdx.x;
    if (e >= EE) return;
    int d = dst[e];
    int p = atomicAdd(&cursor[d], 1);
    csr[row_start[d] + p] = e;
}

// combined adjacency (both endpoints), 2E entries
__global__ void fill_adj2_kernel(const int* __restrict__ src, const int* __restrict__ dst,
                                 const int* __restrict__ rs2, int* cursor2, int* adj2) {
    int e = blockIdx.x * blockDim.x + threadIdx.x;
    if (e >= EE) return;
    int s = src[e];
    int p = atomicAdd(&cursor2[s], 1);
    adj2[rs2[s] + p] = e;
    int t = dst[e];
    int q = atomicAdd(&cursor2[t], 1);
    adj2[rs2[t] + q] = e;
}

// ---------------- cast fp32 -> bf16 (vectorized) ----------------
__global__ void cast_bf_kernel(const float* __restrict__ in, unsigned short* __restrict__ out,
                               int n4) {
    int i = blockIdx.x * blockDim.x + threadIdx.x;
    if (i >= n4) return;
    float4 v = ((const float4*)in)[i];
    ushort4 o;
    o.x = f2bf(v.x); o.y = f2bf(v.y); o.z = f2bf(v.z); o.w = f2bf(v.w);
    ((ushort4*)out)[i] = o;
}

// ---------------- weight transpose + cast: W[K][N] fp32 -> Wt[N][K] bf16 ----------------
__global__ void wtrans_kernel(const float* __restrict__ W, unsigned short* __restrict__ Wt,
                              int K, int N) {
    __shared__ float t[32][33];
    int x = threadIdx.x & 31, y = threadIdx.x >> 5;  // 32 x 8
    int bn = blockIdx.x * 32, bk = blockIdx.y * 32;
#pragma unroll
    for (int i = 0; i < 32; i += 8) t[y + i][x] = W[(size_t)(bk + y + i) * N + bn + x];
    __syncthreads();
#pragma unroll
    for (int i = 0; i < 32; i += 8)
        Wt[(size_t)(bn + y + i) * K + bk + x] = f2bf(t[x][y + i]);
}

// ---------------- z = x + segment_sum(x[src] -> dst), bf16 in/out, F=512 ----------------
__global__ void agg_add_bf_kernel(const unsigned short* __restrict__ X,
                                  unsigned short* __restrict__ Z,
                                  const int* __restrict__ csr, const int* __restrict__ row_start,
                                  const int* __restrict__ src) {
    __shared__ int s_src[256];
    const int node = blockIdx.x, tid = threadIdx.x;
    const unsigned int* Xu = (const unsigned int*)X;
    const int start = row_start[node], end = row_start[node + 1];
    unsigned int self = Xu[(size_t)node * 256 + tid];
    float a0 = bf2f((unsigned short)(self & 0xffff));
    float a1 = bf2f((unsigned short)(self >> 16));
    for (int k0 = start; k0 < end; k0 += 256) {
        int k = k0 + tid;
        if (k < end) s_src[tid] = src[csr[k]];
        __syncthreads();
        int cnt = min(256, end - k0);
        for (int j = 0; j < cnt; ++j) {
            unsigned int v = Xu[(size_t)s_src[j] * 256 + tid];
            a0 += bf2f((unsigned short)(v & 0xffff));
            a1 += bf2f((unsigned short)(v >> 16));
        }
        __syncthreads();
    }
    ((unsigned int*)Z)[(size_t)node * 256 + tid] =
        (unsigned int)f2bf(a0) | ((unsigned int)f2bf(a1) << 16);
}

// ---------------- bf16 MFMA GEMM: C = [relu](A[M,K] @ Bt[N,K]^T + bias) ----------------
template <int RELU, int OUT_BF16>
__global__ __launch_bounds__(256)
void gemm_mfma_kernel(const unsigned short* __restrict__ A,
                      const unsigned short* __restrict__ Bt,
                      const float* __restrict__ bias, void* __restrict__ Cout,
                      int M, int K, int Nn) {
    __shared__ unsigned short lds[2][2][4][128][8];  // 32 KiB
    const int tid = threadIdx.x;
    const int wid = tid >> 6, lane = tid & 63;
    const int brow = blockIdx.y * 128, bcol = blockIdx.x * 128;
    const int wr = wid >> 1, wc = wid & 1;
    const int khi = lane >> 4, r15 = lane & 15;

    f32x4 acc[4][4] = {};

    const int q0 = wid * 2, q1 = wid * 2 + 1;
    const int kh0 = q0 >> 1, rh0 = q0 & 1;
    const int kh1 = q1 >> 1, rh1 = q1 & 1;
    int ar0 = brow + rh0 * 64 + lane; ar0 = ar0 < M ? ar0 : M - 1;
    int ar1 = brow + rh1 * 64 + lane; ar1 = ar1 < M ? ar1 : M - 1;
    const int bc0 = bcol + rh0 * 64 + lane;
    const int bc1 = bcol + rh1 * 64 + lane;
    const unsigned short* gA0 = A + (size_t)ar0 * K + kh0 * 8;
    const unsigned short* gA1 = A + (size_t)ar1 * K + kh1 * 8;
    const unsigned short* gB0 = Bt + (size_t)bc0 * K + kh0 * 8;
    const unsigned short* gB1 = Bt + (size_t)bc1 * K + kh1 * 8;

#define GLL(gp, lp) __builtin_amdgcn_global_load_lds( \
        (const __attribute__((address_space(1))) unsigned int*)(gp), \
        (__attribute__((address_space(3))) unsigned int*)(lp), 16, 0, 0)
#define STAGE(buf, kt) do { const int koff = (kt) * 32; \
        GLL(gA0 + koff, &lds[buf][0][kh0][rh0 * 64][0]); \
        GLL(gA1 + koff, &lds[buf][0][kh1][rh1 * 64][0]); \
        GLL(gB0 + koff, &lds[buf][1][kh0][rh0 * 64][0]); \
        GLL(gB1 + koff, &lds[buf][1][kh1][rh1 * 64][0]); \
    } while (0)

    const int NT = K >> 5;
    STAGE(0, 0);
    for (int kt = 0; kt < NT; ++kt) {
        const int cur = kt & 1;
        __syncthreads();
        if (kt + 1 < NT) STAGE(cur ^ 1, kt + 1);
        short8 af[4], bfv[4];
#pragma unroll
        for (int m = 0; m < 4; ++m)
            af[m] = *(const short8*)&lds[cur][0][khi][wr * 64 + m * 16 + r15][0];
#pragma unroll
        for (int n = 0; n < 4; ++n)
            bfv[n] = *(const short8*)&lds[cur][1][khi][wc * 64 + n * 16 + r15][0];
#pragma unroll
        for (int m = 0; m < 4; ++m)
#pragma unroll
            for (int n = 0; n < 4; ++n)
                acc[m][n] =
                    __builtin_amdgcn_mfma_f32_16x16x32_bf16(af[m], bfv[n], acc[m][n], 0, 0, 0);
    }
#undef STAGE
#undef GLL

#pragma unroll
    for (int m = 0; m < 4; ++m) {
#pragma unroll
        for (int n = 0; n < 4; ++n) {
            const int col = bcol + wc * 64 + n * 16 + r15;
            const float bb = bias ? bias[col] : 0.f;
            f32x4 v = acc[m][n];
#pragma unroll
            for (int r = 0; r < 4; ++r) {
                const int row = brow + wr * 64 + m * 16 + khi * 4 + r;
                if (row < M) {
                    float o = v[r] + bb;
                    if (RELU) o = fmaxf(o, 0.f);
                    if (OUT_BF16)
                        ((unsigned short*)Cout)[(size_t)row * Nn + col] = f2bf(o);
                    else
                        ((float*)Cout)[(size_t)row * Nn + col] = o;
                }
            }
        }
    }
}

// ---------------- BatchNorm (training stats, biased var) ----------------
__global__ void bn_stats_kernel(const float* __restrict__ h, float* cs, float* csq) {
    int col = threadIdx.x;  // 256
    int r0 = blockIdx.x * 100;
    int r1 = min(r0 + 100, NN);
    float s = 0.f, sq = 0.f;
    for (int r = r0; r < r1; r++) {
        float v = h[(size_t)r * 256 + col];
        s += v;
        sq += v * v;
    }
    atomicAdd(&cs[col], s);
    atomicAdd(&csq[col], sq);
}

__global__ void bn_apply_bf_kernel(const float* __restrict__ h, const float* __restrict__ cs,
                                   const float* __restrict__ csq, const float* __restrict__ g,
                                   const float* __restrict__ b, unsigned short* __restrict__ out) {
    int i = blockIdx.x * blockDim.x + threadIdx.x;
    if (i >= NN * 256) return;
    int col = i & 255;
    float mu = cs[col] * (1.f / NN);
    float var = csq[col] * (1.f / NN) - mu * mu;
    float inv = rsqrtf(var + 1e-5f);
    out[i] = f2bf((h[i] - mu) * inv * g[col] + b[col]);
}

// ---------------- FUSED GATv2: logits + online softmax + PV + alpha write ----------------
// One wave per dst node. xr[node] cached in regs; each in-edge's xl[src] row gathered ONCE
// and used for both logit and output accumulation (flash-attention style online softmax).
// Logits cached in 4 regs/lane for deg<=64 (alpha written without re-gather);
// deg>64 falls back to a recompute sweep (probability ~0 for this graph).
__global__ void gat_fused_kernel(const unsigned short* __restrict__ xl,
                                 const unsigned short* __restrict__ xr,
                                 const int* __restrict__ csr, const int* __restrict__ rs,
                                 const int* __restrict__ src, const float* __restrict__ att,
                                 const float* __restrict__ gatb,
                                 float* __restrict__ alpha, float* __restrict__ out) {
    const int lane = threadIdx.x & 63;
    const int wave = threadIdx.x >> 6;
    const int node = blockIdx.x * 4 + wave;
    if (node >= NN) return;
    const int start = rs[node], end = rs[node + 1];
    const int deg = end - start;
    const int h = lane >> 4;
    const int l15 = lane & 15;

    // this lane owns dims [lane*4 .. lane*4+3] of the 256-wide row (head h, d = l15*4+j)
    const float4 attv = ((const float4*)att)[lane];
    const uint2 uxr = ((const uint2*)(xr + (size_t)node * 256))[lane];
    const float xr0 = bf2f((unsigned short)(uxr.x & 0xffff));
    const float xr1 = bf2f((unsigned short)(uxr.x >> 16));
    const float xr2 = bf2f((unsigned short)(uxr.y & 0xffff));
    const float xr3 = bf2f((unsigned short)(uxr.y >> 16));

    float m = -1e30f, S = 0.f;
    float O0 = 0.f, O1 = 0.f, O2 = 0.f, O3 = 0.f;
    float lg0 = 0.f, lg1 = 0.f, lg2 = 0.f, lg3 = 0.f;  // logit cache (deg<=64 fast path)
    const bool fast = (deg <= 64);
    int eid = 0;

    for (int base = start; base < end; base += 64) {
        const int cnt = min(64, end - base);
        eid = (lane < cnt) ? csr[base + lane] : 0;
        int sid = (lane < cnt) ? src[eid] : 0;
        for (int i = 0; i < cnt; ++i) {
            const int s = __shfl(sid, i);
            const uint2 u = ((const uint2*)(xl + (size_t)s * 256))[lane];
            const float x0 = bf2f((unsigned short)(u.x & 0xffff));
            const float x1 = bf2f((unsigned short)(u.x >> 16));
            const float x2 = bf2f((unsigned short)(u.y & 0xffff));
            const float x3 = bf2f((unsigned short)(u.y >> 16));
            float a0 = x0 + xr0; a0 = a0 > 0.f ? a0 : 0.2f * a0;
            float a1 = x1 + xr1; a1 = a1 > 0.f ? a1 : 0.2f * a1;
            float a2 = x2 + xr2; a2 = a2 > 0.f ? a2 : 0.2f * a2;
            float a3 = x3 + xr3; a3 = a3 > 0.f ? a3 : 0.2f * a3;
            float p = a0 * attv.x + a1 * attv.y + a2 * attv.z + a3 * attv.w;
#pragma unroll
            for (int o = 1; o < 16; o <<= 1) p += __shfl_xor(p, o);
            // p = logit of this edge for head h (replicated within 16-lane group)
            if (fast && l15 == (i & 15)) {
                const int t = i >> 4;
                if (t == 0) lg0 = p;
                else if (t == 1) lg1 = p;
                else if (t == 2) lg2 = p;
                else lg3 = p;
            }
            const float mn = fmaxf(m, p);
            const float sc = __expf(m - mn);   // ==1 when max unchanged
            const float w = __expf(p - mn);
            S = S * sc + w;
            O0 = O0 * sc + w * x0;
            O1 = O1 * sc + w * x1;
            O2 = O2 * sc + w * x2;
            O3 = O3 * sc + w * x3;
            m = mn;
        }
    }

    // output = O/S + bias  (deg==0 -> bias only, matching segment_sum semantics)
    const float rS = (deg > 0) ? 1.f / S : 0.f;
    const float4 bv = ((const float4*)gatb)[lane];
    float4 ov;
    ov.x = O0 * rS + bv.x; ov.y = O1 * rS + bv.y;
    ov.z = O2 * rS + bv.z; ov.w = O3 * rS + bv.w;
    ((float4*)(out + (size_t)node * 256))[lane] = ov;

    if (deg == 0) return;
    if (fast) {
        // eid regs still hold the single chunk's edge ids
#pragma unroll
        for (int t = 0; t < 4; ++t) {
            const int k = l15 + t * 16;
            if (k < deg) {
                const int e = __shfl(eid, k);
                const float l = (t == 0) ? lg0 : (t == 1) ? lg1 : (t == 2) ? lg2 : lg3;
                alpha[(size_t)e * 4 + h] = __expf(l - m) * rS;
            }
        }
    } else {
        // rare: recompute logits and write normalized alpha
        for (int base = start; base < end; base += 64) {
            const int cnt = min(64, end - base);
            const int eid2 = (lane < cnt) ? csr[base + lane] : 0;
            const int sid2 = (lane < cnt) ? src[eid2] : 0;
            for (int i = 0; i < cnt; ++i) {
                const int s = __shfl(sid2, i);
                const uint2 u = ((const uint2*)(xl + (size_t)s * 256))[lane];
                float a0 = bf2f((unsigned short)(u.x & 0xffff)) + xr0; a0 = a0 > 0.f ? a0 : 0.2f * a0;
                float a1 = bf2f((unsigned short)(u.x >> 16)) + xr1;    a1 = a1 > 0.f ? a1 : 0.2f * a1;
                float a2 = bf2f((unsigned short)(u.y & 0xffff)) + xr2; a2 = a2 > 0.f ? a2 : 0.2f * a2;
                float a3 = bf2f((unsigned short)(u.y >> 16)) + xr3;    a3 = a3 > 0.f ? a3 : 0.2f * a3;
                float p = a0 * attv.x + a1 * attv.y + a2 * attv.z + a3 * attv.w;
#pragma unroll
                for (int o = 1; o < 16; o <<= 1) p += __shfl_xor(p, o);
                const int e = __shfl(eid2, i);
                if (l15 == 0) alpha[(size_t)e * 4 + h] = __expf(p - m) * rS;
            }
        }
    }
}

// ---------------- node_att via combined-CSR gather (no atomics) ----------------
// edge_w[h][e] == abuf[h*E + e]  (flat reinterpretation of alpha [E,H])
__global__ void node_att_gather_kernel(const float* __restrict__ abuf,
                                       const int* __restrict__ adj2,
                                       const int* __restrict__ rs2, float* __restrict__ na) {
    int lane = threadIdx.x & 63;
    int wave = threadIdx.x >> 6;
    int node = blockIdx.x * 4 + wave;
    if (node >= NN) return;
    int start = rs2[node], end = rs2[node + 1];
    float s0 = 0.f, s1 = 0.f, s2 = 0.f, s3 = 0.f;
    for (int k = start + lane; k < end; k += 64) {
        int e = adj2[k];
        s0 += abuf[e];
        s1 += abuf[EE + e];
        s2 += abuf[2 * EE + e];
        s3 += abuf[3 * EE + e];
    }
#pragma unroll
    for (int o = 32; o > 0; o >>= 1) {
        s0 += __shfl_xor(s0, o);
        s1 += __shfl_xor(s1, o);
        s2 += __shfl_xor(s2, o);
        s3 += __shfl_xor(s3, o);
    }
    if (lane == 0) {
        na[node] = s0;
        na[NN + node] = s1;
        na[2 * NN + node] = s2;
        na[3 * NN + node] = s3;
    }
}

// ---------------- out_edge = mean over heads (coalesced) ----------------
__global__ void edge_mean_kernel(const float* __restrict__ abuf, float* __restrict__ out_edge) {
    int e = blockIdx.x * blockDim.x + threadIdx.x;
    if (e >= EE) return;
    out_edge[e] = 0.25f * (abuf[e] + abuf[EE + e] + abuf[2 * EE + e] + abuf[3 * EE + e]);
}

__global__ void head_stats_kernel(const float* __restrict__ na, const int* __restrict__ deg_tot,
                                  float* hm, float* hs) {
    __shared__ float red[1024];
    int h = blockIdx.x;
    int tid = threadIdx.x;
    float m = -1e30f;
    for (int i = tid; i < NN; i += 1024) {
        float v = na[h * NN + i] / ((float)deg_tot[i] + 1e-9f);
        m = fmaxf(m, v);
    }
    red[tid] = m;
    __syncthreads();
    for (int o = 512; o > 0; o >>= 1) {
        if (tid < o) red[tid] = fmaxf(red[tid], red[tid + o]);
        __syncthreads();
    }
    m = red[0];
    __syncthreads();
    float s = 0.f;
    for (int i = tid; i < NN; i += 1024) {
        float v = na[h * NN + i] / ((float)deg_tot[i] + 1e-9f);
        s += __expf(v - m);
    }
    red[tid] = s;
    __syncthreads();
    for (int o = 512; o > 0; o >>= 1) {
        if (tid < o) red[tid] += red[tid + o];
        __syncthreads();
    }
    if (tid == 0) {
        hm[h] = m;
        hs[h] = red[0];
    }
}

__global__ void node_out_kernel(const float* __restrict__ na, const int* __restrict__ deg_tot,
                                const float* __restrict__ hm, const float* __restrict__ hs,
                                float* __restrict__ out_node) {
    int i = blockIdx.x * blockDim.x + threadIdx.x;
    if (i >= NN) return;
    float acc = 0.f;
#pragma unroll
    for (int h = 0; h < 4; h++) {
        float v = na[h * NN + i] / ((float)deg_tot[i] + 1e-9f);
        acc += __expf(v - hm[h]) / hs[h];
    }
    out_node[i] = 0.25f * acc;
}

// ---------------- LayerNorm(N*L) + Linear + sigmoid ----------------
__global__ void ln_stats_kernel(const float* __restrict__ x, float* scal) {
    __shared__ float rs[256], rq[256];
    const size_t total = (size_t)NN * 256;
    float s = 0.f, q = 0.f;
    for (size_t i = (size_t)blockIdx.x * blockDim.x + threadIdx.x; i < total;
         i += (size_t)gridDim.x * blockDim.x) {
        float v = x[i];
        s += v;
        q += v * v;
    }
    rs[threadIdx.x] = s;
    rq[threadIdx.x] = q;
    __syncthreads();
    for (int o = 128; o > 0; o >>= 1) {
        if (threadIdx.x < o) {
            rs[threadIdx.x] += rs[threadIdx.x + o];
            rq[threadIdx.x] += rq[threadIdx.x + o];
        }
        __syncthreads();
    }
    if (threadIdx.x == 0) {
        atomicAdd(&scal[0], rs[0]);
        atomicAdd(&scal[1], rq[0]);
    }
}

__global__ void ln_dot_kernel(const float* __restrict__ x, const float* __restrict__ g,
                              const float* __restrict__ b, const float* __restrict__ Wp,
                              float* scal) {
    __shared__ float rs[256];
    const size_t total = (size_t)NN * 256;
    float mu = scal[0] / (float)total;
    float var = scal[1] / (float)total - mu * mu;
    float inv = rsqrtf(var + 1e-5f);
    float s = 0.f;
    for (size_t i = (size_t)blockIdx.x * blockDim.x + threadIdx.x; i < total;
         i += (size_t)gridDim.x * blockDim.x) {
        float v = (x[i] - mu) * inv * g[i] + b[i];
        s += v * Wp[i];
    }
    rs[threadIdx.x] = s;
    __syncthreads();
    for (int o = 128; o > 0; o >>= 1) {
        if (threadIdx.x < o) rs[threadIdx.x] += rs[threadIdx.x + o];
        __syncthreads();
    }
    if (threadIdx.x == 0) atomicAdd(&scal[2], rs[0]);
}

__global__ void finalize_kernel(const float* __restrict__ scal, const float* __restrict__ bp,
                                float* __restrict__ out) {
    float z = scal[2] + bp[0];
    out[0] = 1.f / (1.f + __expf(-z));
}

extern "C" void kernel_launch(void* const* d_in, const int* in_sizes, int n_in,
                              void* d_out, int out_size, void* d_ws, size_t ws_size,
                              hipStream_t stream) {
    const float* x    = (const float*)d_in[0];
    const int* ei     = (const int*)d_in[1];
    const float* W1a  = (const float*)d_in[3];
    const float* b1a  = (const float*)d_in[4];
    const float* W1b  = (const float*)d_in[5];
    const float* b1b  = (const float*)d_in[6];
    const float* W2a  = (const float*)d_in[7];
    const float* b2a  = (const float*)d_in[8];
    const float* W2b  = (const float*)d_in[9];
    const float* b2b  = (const float*)d_in[10];
    const float* bn_g = (const float*)d_in[11];
    const float* bn_b = (const float*)d_in[12];
    const float* Wl   = (const float*)d_in[13];
    const float* Wr   = (const float*)d_in[14];
    const float* att  = (const float*)d_in[15];
    const float* gatb = (const float*)d_in[16];
    const float* ln_g = (const float*)d_in[17];
    const float* ln_b = (const float*)d_in[18];
    const float* Wp   = (const float*)d_in[19];
    const float* bp   = (const float*)d_in[20];

    const int* src = ei;
    const int* dst = ei + EE;

    float* out = (float*)d_out;
    float* out_pred = out;
    float* out_node = out + 1;
    float* out_edge = out + 1 + NN;

    // ---- workspace layout ----
    unsigned short* B0 = (unsigned short*)d_ws;
    unsigned short* B1 = B0 + (size_t)NN * 512;
    unsigned short* B2 = B1 + (size_t)NN * 512;
    unsigned short* B3 = B2 + (size_t)NN * 512;
    float* hbuf = (float*)B0;  // N*256 fp32 == N*512 bf16 bytes
    unsigned short* xl = B1;
    unsigned short* xr = B3;
    float* gout = (float*)B0;

    unsigned short* W1at = B3 + (size_t)NN * 512;
    unsigned short* W1bt = W1at + 512 * 512;
    unsigned short* W2at = W1bt + 512 * 512;
    unsigned short* W2bt = W2at + 256 * 512;
    unsigned short* Wlt  = W2bt + 256 * 256;
    unsigned short* Wrt  = Wlt + 256 * 256;
    float* alpha = (float*)(Wrt + 256 * 256);  // E*4 fp32, 16B-aligned
    float* na    = alpha + (size_t)EE * 4;     // 4*N
    float* csum  = na + 4 * NN;                // 256
    float* csq_  = csum + 256;                 // 256
    float* hm    = csq_ + 256;                 // 4
    float* hs    = hm + 4;                     // 4
    float* scal  = hs + 4;                     // 8
    int* deg_in     = (int*)(scal + 8);        // N
    int* deg_tot    = deg_in + NN;             // N
    int* row_start  = deg_tot + NN;            // N+1
    int* row_start2 = row_start + NN + 1;      // N+1
    int* cursor     = row_start2 + NN + 1;     // N
    int* cursor2    = cursor + NN;             // N
    int* csr        = cursor2 + NN;            // E
    int* adj2       = csr + EE;                // 2E

    hipMemsetAsync(csum, 0, (size_t)(256 + 256 + 4 + 4 + 8) * sizeof(float), stream);
    hipMemsetAsync(deg_in, 0, (size_t)(6 * NN + 2) * sizeof(int), stream);

    const int EB = (EE + 255) / 256;

    // weight prep (bf16, transposed to [N][K])
    wtrans_kernel<<<dim3(16, 16), 256, 0, stream>>>(W1a, W1at, 512, 512);
    wtrans_kernel<<<dim3(16, 16), 256, 0, stream>>>(W1b, W1bt, 512, 512);
    wtrans_kernel<<<dim3(8, 16), 256, 0, stream>>>(W2a, W2at, 512, 256);
    wtrans_kernel<<<dim3(8, 8), 256, 0, stream>>>(W2b, W2bt, 256, 256);
    wtrans_kernel<<<dim3(8, 8), 256, 0, stream>>>(Wl, Wlt, 256, 256);
    wtrans_kernel<<<dim3(8, 8), 256, 0, stream>>>(Wr, Wrt, 256, 256);

    cast_bf_kernel<<<(NN * 512 / 4 + 255) / 256, 256, 0, stream>>>(x, B0, NN * 512 / 4);

    deg_kernel<<<EB, 256, 0, stream>>>(src, dst, deg_in, deg_tot);
    scan_kernel<<<1, 1024, 0, stream>>>(deg_in, row_start, NN);
    scan_kernel<<<1, 1024, 0, stream>>>(deg_tot, row_start2, NN);
    fill_csr_kernel<<<EB, 256, 0, stream>>>(dst, row_start, cursor, csr);
    fill_adj2_kernel<<<EB, 256, 0, stream>>>(src, dst, row_start2, cursor2, adj2);

    // GIN layer 1
    agg_add_bf_kernel<<<NN, 256, 0, stream>>>(B0, B1, csr, row_start, src);  // z1
    gemm_mfma_kernel<1, 1><<<dim3(4, 157), 256, 0, stream>>>(B1, W1at, b1a, B2, NN, 512, 512);
    gemm_mfma_kernel<1, 1><<<dim3(4, 157), 256, 0, stream>>>(B2, W1bt, b1b, B3, NN, 512, 512);
    // GIN layer 2
    agg_add_bf_kernel<<<NN, 256, 0, stream>>>(B3, B0, csr, row_start, src);  // z2
    gemm_mfma_kernel<1, 1><<<dim3(2, 157), 256, 0, stream>>>(B0, W2at, b2a, B1, NN, 512, 256);
    gemm_mfma_kernel<0, 0><<<dim3(2, 157), 256, 0, stream>>>(B1, W2bt, b2b, hbuf, NN, 256, 256);

    // BatchNorm -> bf16 h_bn in B2
    bn_stats_kernel<<<200, 256, 0, stream>>>(hbuf, csum, csq_);
    bn_apply_bf_kernel<<<(NN * 256 + 255) / 256, 256, 0, stream>>>(hbuf, csum, csq_, bn_g, bn_b,
                                                                   B2);

    // GATv2 projections (bf16 out)
    gemm_mfma_kernel<0, 1><<<dim3(2, 157), 256, 0, stream>>>(B2, Wlt, nullptr, xl, NN, 256, 256);
    gemm_mfma_kernel<0, 1><<<dim3(2, 157), 256, 0, stream>>>(B2, Wrt, nullptr, xr, NN, 256, 256);

    // fused GATv2 edge phase: logits + softmax + PV + alpha
    gat_fused_kernel<<<(NN + 3) / 4, 256, 0, stream>>>(xl, xr, csr, row_start, src, att, gatb,
                                                       alpha, gout);

    node_att_gather_kernel<<<NN / 4, 256, 0, stream>>>(alpha, adj2, row_start2, na);
    edge_mean_kernel<<<EB, 256, 0, stream>>>(alpha, out_edge);
    head_stats_kernel<<<4, 1024, 0, stream>>>(na, deg_tot, hm, hs);
    node_out_kernel<<<(NN + 255) / 256, 256, 0, stream>>>(na, deg_tot, hm, hs, out_node);

    ln_stats_kernel<<<2560, 256, 0, stream>>>(gout, scal);
    ln_dot_kernel<<<2560, 256, 0, stream>>>(gout, ln_g, ln_b, Wp, scal);
    finalize_kernel<<<1, 1, 0, stream>>>(scal, bp, out_pred);
}

// Round 9
// 703.179 us; speedup vs baseline: 2.4547x; 1.1814x over previous
//
#include <hip/hip_runtime.h>
#include <hip/hip_bf16.h>

#define NN 20000
#define TT 512
#define LL 256
#define HH 4
#define DD 64
#define EE 320000

typedef __attribute__((ext_vector_type(8))) short short8;
typedef __attribute__((ext_vector_type(4))) float f32x4;

__device__ __forceinline__ float bf2f(unsigned short u) {
    return __uint_as_float((unsigned)u << 16);
}
__device__ __forceinline__ unsigned short f2bf(float f) {
    __hip_bfloat16 h = __float2bfloat16(f);
    unsigned short r;
    __builtin_memcpy(&r, &h, 2);
    return r;
}

// ---------------- degree / CSR build ----------------
__global__ void deg_kernel(const int* __restrict__ src, const int* __restrict__ dst,
                           int* deg_in, int* deg_tot) {
    int e = blockIdx.x * blockDim.x + threadIdx.x;
    if (e >= EE) return;
    atomicAdd(&deg_in[dst[e]], 1);
    atomicAdd(&deg_tot[src[e]], 1);
    atomicAdd(&deg_tot[dst[e]], 1);
}

// two independent exclusive scans in one dispatch (block 0: deg0->rs0, block 1: deg1->rs1)
__global__ void scan2_kernel(const int* __restrict__ deg0, int* rs0,
                             const int* __restrict__ deg1, int* rs1, int n) {
    __shared__ int sm[1024];
    __shared__ int s_carry;
    const int* deg = (blockIdx.x == 0) ? deg0 : deg1;
    int* row_start = (blockIdx.x == 0) ? rs0 : rs1;
    int tid = threadIdx.x;
    if (tid == 0) s_carry = 0;
    __syncthreads();
    for (int base = 0; base < n; base += 1024) {
        int i = base + tid;
        int v = (i < n) ? deg[i] : 0;
        sm[tid] = v;
        __syncthreads();
        for (int off = 1; off < 1024; off <<= 1) {
            int t = (tid >= off) ? sm[tid - off] : 0;
            __syncthreads();
            sm[tid] += t;
            __syncthreads();
        }
        int incl = sm[tid];
        int carry = s_carry;
        if (i < n) row_start[i] = carry + incl - v;
        __syncthreads();
        if (tid == 1023) s_carry = carry + sm[1023];
        __syncthreads();
    }
    if (tid == 0) row_start[n] = s_carry;
}

__global__ void fill_csr_kernel(const int* __restrict__ dst, const int* __restrict__ row_start,
                                int* cursor, int* csr) {
    int e = blockIdx.x * blockDim.x + threadIdx.x;
    if (e >= EE) return;
    int d = dst[e];
    int p = atomicAdd(&cursor[d], 1);
    csr[row_start[d] + p] = e;
}

// combined adjacency (both endpoints), 2E entries
__global__ void fill_adj2_kernel(const int* __restrict__ src, const int* __restrict__ dst,
                                 const int* __restrict__ rs2, int* cursor2, int* adj2) {
    int e = blockIdx.x * blockDim.x + threadIdx.x;
    if (e >= EE) return;
    int s = src[e];
    int p = atomicAdd(&cursor2[s], 1);
    adj2[rs2[s] + p] = e;
    int t = dst[e];
    int q = atomicAdd(&cursor2[t], 1);
    adj2[rs2[t] + q] = e;
}

// ---------------- cast fp32 -> bf16 (vectorized) ----------------
__global__ void cast_bf_kernel(const float* __restrict__ in, unsigned short* __restrict__ out,
                               int n4) {
    int i = blockIdx.x * blockDim.x + threadIdx.x;
    if (i >= n4) return;
    float4 v = ((const float4*)in)[i];
    ushort4 o;
    o.x = f2bf(v.x); o.y = f2bf(v.y); o.z = f2bf(v.z); o.w = f2bf(v.w);
    ((ushort4*)out)[i] = o;
}

// ---------------- weight transpose + cast: W[K][N] fp32 -> Wt[N][K] bf16 ----------------
__global__ void wtrans_kernel(const float* __restrict__ W, unsigned short* __restrict__ Wt,
                              int K, int N) {
    __shared__ float t[32][33];
    int x = threadIdx.x & 31, y = threadIdx.x >> 5;  // 32 x 8
    int bn = blockIdx.x * 32, bk = blockIdx.y * 32;
#pragma unroll
    for (int i = 0; i < 32; i += 8) t[y + i][x] = W[(size_t)(bk + y + i) * N + bn + x];
    __syncthreads();
#pragma unroll
    for (int i = 0; i < 32; i += 8)
        Wt[(size_t)(bn + y + i) * K + bk + x] = f2bf(t[x][y + i]);
}

// ---------------- z = x + segment_sum(x[src] -> dst), bf16 in/out, F=512 ----------------
__global__ void agg_add_bf_kernel(const unsigned short* __restrict__ X,
                                  unsigned short* __restrict__ Z,
                                  const int* __restrict__ csr, const int* __restrict__ row_start,
                                  const int* __restrict__ src) {
    __shared__ int s_src[256];
    const int node = blockIdx.x, tid = threadIdx.x;
    const unsigned int* Xu = (const unsigned int*)X;
    const int start = row_start[node], end = row_start[node + 1];
    unsigned int self = Xu[(size_t)node * 256 + tid];
    float a0 = bf2f((unsigned short)(self & 0xffff));
    float a1 = bf2f((unsigned short)(self >> 16));
    for (int k0 = start; k0 < end; k0 += 256) {
        int k = k0 + tid;
        if (k < end) s_src[tid] = src[csr[k]];
        __syncthreads();
        int cnt = min(256, end - k0);
        for (int j = 0; j < cnt; ++j) {
            unsigned int v = Xu[(size_t)s_src[j] * 256 + tid];
            a0 += bf2f((unsigned short)(v & 0xffff));
            a1 += bf2f((unsigned short)(v >> 16));
        }
        __syncthreads();
    }
    ((unsigned int*)Z)[(size_t)node * 256 + tid] =
        (unsigned int)f2bf(a0) | ((unsigned int)f2bf(a1) << 16);
}

// ---------------- bf16 MFMA GEMM: C = [relu](A[M,K] @ Bt[N,K]^T + bias) ----------------
template <int RELU, int OUT_BF16>
__global__ __launch_bounds__(256)
void gemm_mfma_kernel(const unsigned short* __restrict__ A,
                      const unsigned short* __restrict__ Bt,
                      const float* __restrict__ bias, void* __restrict__ Cout,
                      int M, int K, int Nn) {
    __shared__ unsigned short lds[2][2][4][128][8];  // 32 KiB
    const int tid = threadIdx.x;
    const int wid = tid >> 6, lane = tid & 63;
    const int brow = blockIdx.y * 128, bcol = blockIdx.x * 128;
    const int wr = wid >> 1, wc = wid & 1;
    const int khi = lane >> 4, r15 = lane & 15;

    f32x4 acc[4][4] = {};

    const int q0 = wid * 2, q1 = wid * 2 + 1;
    const int kh0 = q0 >> 1, rh0 = q0 & 1;
    const int kh1 = q1 >> 1, rh1 = q1 & 1;
    int ar0 = brow + rh0 * 64 + lane; ar0 = ar0 < M ? ar0 : M - 1;
    int ar1 = brow + rh1 * 64 + lane; ar1 = ar1 < M ? ar1 : M - 1;
    const int bc0 = bcol + rh0 * 64 + lane;
    const int bc1 = bcol + rh1 * 64 + lane;
    const unsigned short* gA0 = A + (size_t)ar0 * K + kh0 * 8;
    const unsigned short* gA1 = A + (size_t)ar1 * K + kh1 * 8;
    const unsigned short* gB0 = Bt + (size_t)bc0 * K + kh0 * 8;
    const unsigned short* gB1 = Bt + (size_t)bc1 * K + kh1 * 8;

#define GLL(gp, lp) __builtin_amdgcn_global_load_lds( \
        (const __attribute__((address_space(1))) unsigned int*)(gp), \
        (__attribute__((address_space(3))) unsigned int*)(lp), 16, 0, 0)
#define STAGE(buf, kt) do { const int koff = (kt) * 32; \
        GLL(gA0 + koff, &lds[buf][0][kh0][rh0 * 64][0]); \
        GLL(gA1 + koff, &lds[buf][0][kh1][rh1 * 64][0]); \
        GLL(gB0 + koff, &lds[buf][1][kh0][rh0 * 64][0]); \
        GLL(gB1 + koff, &lds[buf][1][kh1][rh1 * 64][0]); \
    } while (0)

    const int NT = K >> 5;
    STAGE(0, 0);
    for (int kt = 0; kt < NT; ++kt) {
        const int cur = kt & 1;
        __syncthreads();
        if (kt + 1 < NT) STAGE(cur ^ 1, kt + 1);
        short8 af[4], bfv[4];
#pragma unroll
        for (int m = 0; m < 4; ++m)
            af[m] = *(const short8*)&lds[cur][0][khi][wr * 64 + m * 16 + r15][0];
#pragma unroll
        for (int n = 0; n < 4; ++n)
            bfv[n] = *(const short8*)&lds[cur][1][khi][wc * 64 + n * 16 + r15][0];
#pragma unroll
        for (int m = 0; m < 4; ++m)
#pragma unroll
            for (int n = 0; n < 4; ++n)
                acc[m][n] =
                    __builtin_amdgcn_mfma_f32_16x16x32_bf16(af[m], bfv[n], acc[m][n], 0, 0, 0);
    }
#undef STAGE
#undef GLL

#pragma unroll
    for (int m = 0; m < 4; ++m) {
#pragma unroll
        for (int n = 0; n < 4; ++n) {
            const int col = bcol + wc * 64 + n * 16 + r15;
            const float bb = bias ? bias[col] : 0.f;
            f32x4 v = acc[m][n];
#pragma unroll
            for (int r = 0; r < 4; ++r) {
                const int row = brow + wr * 64 + m * 16 + khi * 4 + r;
                if (row < M) {
                    float o = v[r] + bb;
                    if (RELU) o = fmaxf(o, 0.f);
                    if (OUT_BF16)
                        ((unsigned short*)Cout)[(size_t)row * Nn + col] = f2bf(o);
                    else
                        ((float*)Cout)[(size_t)row * Nn + col] = o;
                }
            }
        }
    }
}

// ---------------- BatchNorm (training stats, biased var) ----------------
__global__ void bn_stats_kernel(const float* __restrict__ h, float* cs, float* csq) {
    int col = threadIdx.x;  // 256
    int r0 = blockIdx.x * 100;
    int r1 = min(r0 + 100, NN);
    float s = 0.f, sq = 0.f;
    for (int r = r0; r < r1; r++) {
        float v = h[(size_t)r * 256 + col];
        s += v;
        sq += v * v;
    }
    atomicAdd(&cs[col], s);
    atomicAdd(&csq[col], sq);
}

__global__ void bn_apply_bf_kernel(const float* __restrict__ h, const float* __restrict__ cs,
                                   const float* __restrict__ csq, const float* __restrict__ g,
                                   const float* __restrict__ b, unsigned short* __restrict__ out) {
    int i = blockIdx.x * blockDim.x + threadIdx.x;
    if (i >= NN * 256) return;
    int col = i & 255;
    float mu = cs[col] * (1.f / NN);
    float var = csq[col] * (1.f / NN) - mu * mu;
    float inv = rsqrtf(var + 1e-5f);
    out[i] = f2bf((h[i] - mu) * inv * g[col] + b[col]);
}

// ---------------- FUSED GATv2: logits + online softmax + PV + alpha write ----------------
__global__ void gat_fused_kernel(const unsigned short* __restrict__ xl,
                                 const unsigned short* __restrict__ xr,
                                 const int* __restrict__ csr, const int* __restrict__ rs,
                                 const int* __restrict__ src, const float* __restrict__ att,
                                 const float* __restrict__ gatb,
                                 float* __restrict__ alpha, float* __restrict__ out) {
    const int lane = threadIdx.x & 63;
    const int wave = threadIdx.x >> 6;
    const int node = blockIdx.x * 4 + wave;
    if (node >= NN) return;
    const int start = rs[node], end = rs[node + 1];
    const int deg = end - start;
    const int h = lane >> 4;
    const int l15 = lane & 15;

    const float4 attv = ((const float4*)att)[lane];
    const uint2 uxr = ((const uint2*)(xr + (size_t)node * 256))[lane];
    const float xr0 = bf2f((unsigned short)(uxr.x & 0xffff));
    const float xr1 = bf2f((unsigned short)(uxr.x >> 16));
    const float xr2 = bf2f((unsigned short)(uxr.y & 0xffff));
    const float xr3 = bf2f((unsigned short)(uxr.y >> 16));

    float m = -1e30f, S = 0.f;
    float O0 = 0.f, O1 = 0.f, O2 = 0.f, O3 = 0.f;
    float lg0 = 0.f, lg1 = 0.f, lg2 = 0.f, lg3 = 0.f;
    const bool fast = (deg <= 64);
    int eid = 0;

    for (int base = start; base < end; base += 64) {
        const int cnt = min(64, end - base);
        eid = (lane < cnt) ? csr[base + lane] : 0;
        int sid = (lane < cnt) ? src[eid] : 0;
        for (int i = 0; i < cnt; ++i) {
            const int s = __shfl(sid, i);
            const uint2 u = ((const uint2*)(xl + (size_t)s * 256))[lane];
            const float x0 = bf2f((unsigned short)(u.x & 0xffff));
            const float x1 = bf2f((unsigned short)(u.x >> 16));
            const float x2 = bf2f((unsigned short)(u.y & 0xffff));
            const float x3 = bf2f((unsigned short)(u.y >> 16));
            float a0 = x0 + xr0; a0 = a0 > 0.f ? a0 : 0.2f * a0;
            float a1 = x1 + xr1; a1 = a1 > 0.f ? a1 : 0.2f * a1;
            float a2 = x2 + xr2; a2 = a2 > 0.f ? a2 : 0.2f * a2;
            float a3 = x3 + xr3; a3 = a3 > 0.f ? a3 : 0.2f * a3;
            float p = a0 * attv.x + a1 * attv.y + a2 * attv.z + a3 * attv.w;
#pragma unroll
            for (int o = 1; o < 16; o <<= 1) p += __shfl_xor(p, o);
            if (fast && l15 == (i & 15)) {
                const int t = i >> 4;
                if (t == 0) lg0 = p;
                else if (t == 1) lg1 = p;
                else if (t == 2) lg2 = p;
                else lg3 = p;
            }
            const float mn = fmaxf(m, p);
            const float sc = __expf(m - mn);
            const float w = __expf(p - mn);
            S = S * sc + w;
            O0 = O0 * sc + w * x0;
            O1 = O1 * sc + w * x1;
            O2 = O2 * sc + w * x2;
            O3 = O3 * sc + w * x3;
            m = mn;
        }
    }

    const float rS = (deg > 0) ? 1.f / S : 0.f;
    const float4 bv = ((const float4*)gatb)[lane];
    float4 ov;
    ov.x = O0 * rS + bv.x; ov.y = O1 * rS + bv.y;
    ov.z = O2 * rS + bv.z; ov.w = O3 * rS + bv.w;
    ((float4*)(out + (size_t)node * 256))[lane] = ov;

    if (deg == 0) return;
    if (fast) {
#pragma unroll
        for (int t = 0; t < 4; ++t) {
            const int k = l15 + t * 16;
            if (k < deg) {
                const int e = __shfl(eid, k);
                const float l = (t == 0) ? lg0 : (t == 1) ? lg1 : (t == 2) ? lg2 : lg3;
                alpha[(size_t)e * 4 + h] = __expf(l - m) * rS;
            }
        }
    } else {
        for (int base = start; base < end; base += 64) {
            const int cnt = min(64, end - base);
            const int eid2 = (lane < cnt) ? csr[base + lane] : 0;
            const int sid2 = (lane < cnt) ? src[eid2] : 0;
            for (int i = 0; i < cnt; ++i) {
                const int s = __shfl(sid2, i);
                const uint2 u = ((const uint2*)(xl + (size_t)s * 256))[lane];
                float a0 = bf2f((unsigned short)(u.x & 0xffff)) + xr0; a0 = a0 > 0.f ? a0 : 0.2f * a0;
                float a1 = bf2f((unsigned short)(u.x >> 16)) + xr1;    a1 = a1 > 0.f ? a1 : 0.2f * a1;
                float a2 = bf2f((unsigned short)(u.y & 0xffff)) + xr2; a2 = a2 > 0.f ? a2 : 0.2f * a2;
                float a3 = bf2f((unsigned short)(u.y >> 16)) + xr3;    a3 = a3 > 0.f ? a3 : 0.2f * a3;
                float p = a0 * attv.x + a1 * attv.y + a2 * attv.z + a3 * attv.w;
#pragma unroll
                for (int o = 1; o < 16; o <<= 1) p += __shfl_xor(p, o);
                const int e = __shfl(eid2, i);
                if (l15 == 0) alpha[(size_t)e * 4 + h] = __expf(p - m) * rS;
            }
        }
    }
}

// ---------------- node_att via combined-CSR gather (no atomics) ----------------
__global__ void node_att_gather_kernel(const float* __restrict__ abuf,
                                       const int* __restrict__ adj2,
                                       const int* __restrict__ rs2, float* __restrict__ na) {
    int lane = threadIdx.x & 63;
    int wave = threadIdx.x >> 6;
    int node = blockIdx.x * 4 + wave;
    if (node >= NN) return;
    int start = rs2[node], end = rs2[node + 1];
    float s0 = 0.f, s1 = 0.f, s2 = 0.f, s3 = 0.f;
    for (int k = start + lane; k < end; k += 64) {
        int e = adj2[k];
        s0 += abuf[e];
        s1 += abuf[EE + e];
        s2 += abuf[2 * EE + e];
        s3 += abuf[3 * EE + e];
    }
#pragma unroll
    for (int o = 32; o > 0; o >>= 1) {
        s0 += __shfl_xor(s0, o);
        s1 += __shfl_xor(s1, o);
        s2 += __shfl_xor(s2, o);
        s3 += __shfl_xor(s3, o);
    }
    if (lane == 0) {
        na[node] = s0;
        na[NN + node] = s1;
        na[2 * NN + node] = s2;
        na[3 * NN + node] = s3;
    }
}

// ---------------- out_edge = mean over heads (coalesced) ----------------
__global__ void edge_mean_kernel(const float* __restrict__ abuf, float* __restrict__ out_edge) {
    int e = blockIdx.x * blockDim.x + threadIdx.x;
    if (e >= EE) return;
    out_edge[e] = 0.25f * (abuf[e] + abuf[EE + e] + abuf[2 * EE + e] + abuf[3 * EE + e]);
}

__global__ void head_stats_kernel(const float* __restrict__ na, const int* __restrict__ deg_tot,
                                  float* hm, float* hs) {
    __shared__ float red[1024];
    int h = blockIdx.x;
    int tid = threadIdx.x;
    float m = -1e30f;
    for (int i = tid; i < NN; i += 1024) {
        float v = na[h * NN + i] / ((float)deg_tot[i] + 1e-9f);
        m = fmaxf(m, v);
    }
    red[tid] = m;
    __syncthreads();
    for (int o = 512; o > 0; o >>= 1) {
        if (tid < o) red[tid] = fmaxf(red[tid], red[tid + o]);
        __syncthreads();
    }
    m = red[0];
    __syncthreads();
    float s = 0.f;
    for (int i = tid; i < NN; i += 1024) {
        float v = na[h * NN + i] / ((float)deg_tot[i] + 1e-9f);
        s += __expf(v - m);
    }
    red[tid] = s;
    __syncthreads();
    for (int o = 512; o > 0; o >>= 1) {
        if (tid < o) red[tid] += red[tid + o];
        __syncthreads();
    }
    if (tid == 0) {
        hm[h] = m;
        hs[h] = red[0];
    }
}

__global__ void node_out_kernel(const float* __restrict__ na, const int* __restrict__ deg_tot,
                                const float* __restrict__ hm, const float* __restrict__ hs,
                                float* __restrict__ out_node) {
    int i = blockIdx.x * blockDim.x + threadIdx.x;
    if (i >= NN) return;
    float acc = 0.f;
#pragma unroll
    for (int h = 0; h < 4; h++) {
        float v = na[h * NN + i] / ((float)deg_tot[i] + 1e-9f);
        acc += __expf(v - hm[h]) / hs[h];
    }
    out_node[i] = 0.25f * acc;
}

// ---------------- fused LayerNorm(N*L)+Linear: one pass, 5 sums, block partials ----------------
// pred_z = inv*(S3 - mu*S4) + S5 + bp ; S1=Σx S2=Σx² S3=Σx·g·w S4=Σg·w S5=Σb·w
__global__ void ln_fused_kernel(const float* __restrict__ x, const float* __restrict__ g,
                                const float* __restrict__ b, const float* __restrict__ Wp,
                                float* __restrict__ part) {
    const int total4 = NN * 64;  // N*256/4
    const float4* x4 = (const float4*)x;
    const float4* g4 = (const float4*)g;
    const float4* b4 = (const float4*)b;
    const float4* w4 = (const float4*)Wp;
    float s1 = 0.f, s2 = 0.f, s3 = 0.f, s4 = 0.f, s5 = 0.f;
    for (int i = blockIdx.x * blockDim.x + threadIdx.x; i < total4;
         i += gridDim.x * blockDim.x) {
        float4 xv = x4[i], gv = g4[i], bv = b4[i], wv = w4[i];
        s1 += xv.x + xv.y + xv.z + xv.w;
        s2 += xv.x * xv.x + xv.y * xv.y + xv.z * xv.z + xv.w * xv.w;
        float gw0 = gv.x * wv.x, gw1 = gv.y * wv.y, gw2 = gv.z * wv.z, gw3 = gv.w * wv.w;
        s3 += xv.x * gw0 + xv.y * gw1 + xv.z * gw2 + xv.w * gw3;
        s4 += gw0 + gw1 + gw2 + gw3;
        s5 += bv.x * wv.x + bv.y * wv.y + bv.z * wv.z + bv.w * wv.w;
    }
#pragma unroll
    for (int o = 32; o > 0; o >>= 1) {
        s1 += __shfl_xor(s1, o);
        s2 += __shfl_xor(s2, o);
        s3 += __shfl_xor(s3, o);
        s4 += __shfl_xor(s4, o);
        s5 += __shfl_xor(s5, o);
    }
    __shared__ float sm[4][5];
    int lane = threadIdx.x & 63, wv_ = threadIdx.x >> 6;
    if (lane == 0) {
        sm[wv_][0] = s1; sm[wv_][1] = s2; sm[wv_][2] = s3; sm[wv_][3] = s4; sm[wv_][4] = s5;
    }
    __syncthreads();
    if (threadIdx.x == 0) {
        float t1 = 0.f, t2 = 0.f, t3 = 0.f, t4 = 0.f, t5 = 0.f;
#pragma unroll
        for (int w = 0; w < 4; ++w) {
            t1 += sm[w][0]; t2 += sm[w][1]; t3 += sm[w][2]; t4 += sm[w][3]; t5 += sm[w][4];
        }
        part[0 * 512 + blockIdx.x] = t1;
        part[1 * 512 + blockIdx.x] = t2;
        part[2 * 512 + blockIdx.x] = t3;
        part[3 * 512 + blockIdx.x] = t4;
        part[4 * 512 + blockIdx.x] = t5;
    }
}

__global__ void ln_final_kernel(const float* __restrict__ part, const float* __restrict__ bp,
                                float* __restrict__ out) {
    // 512 threads = 8 waves; reduce part[j*512 + tid]
    float v0 = part[0 * 512 + threadIdx.x];
    float v1 = part[1 * 512 + threadIdx.x];
    float v2 = part[2 * 512 + threadIdx.x];
    float v3 = part[3 * 512 + threadIdx.x];
    float v4 = part[4 * 512 + threadIdx.x];
#pragma unroll
    for (int o = 32; o > 0; o >>= 1) {
        v0 += __shfl_xor(v0, o);
        v1 += __shfl_xor(v1, o);
        v2 += __shfl_xor(v2, o);
        v3 += __shfl_xor(v3, o);
        v4 += __shfl_xor(v4, o);
    }
    __shared__ float sm[8][5];
    int lane = threadIdx.x & 63, wv_ = threadIdx.x >> 6;
    if (lane == 0) {
        sm[wv_][0] = v0; sm[wv_][1] = v1; sm[wv_][2] = v2; sm[wv_][3] = v3; sm[wv_][4] = v4;
    }
    __syncthreads();
    if (threadIdx.x == 0) {
        float S1 = 0.f, S2 = 0.f, S3 = 0.f, S4 = 0.f, S5 = 0.f;
#pragma unroll
        for (int w = 0; w < 8; ++w) {
            S1 += sm[w][0]; S2 += sm[w][1]; S3 += sm[w][2]; S4 += sm[w][3]; S5 += sm[w][4];
        }
        const float M = (float)NN * 256.f;
        float mu = S1 / M;
        float var = S2 / M - mu * mu;
        float inv = rsqrtf(var + 1e-5f);
        float z = inv * (S3 - mu * S4) + S5 + bp[0];
        out[0] = 1.f / (1.f + __expf(-z));
    }
}

extern "C" void kernel_launch(void* const* d_in, const int* in_sizes, int n_in,
                              void* d_out, int out_size, void* d_ws, size_t ws_size,
                              hipStream_t stream) {
    const float* x    = (const float*)d_in[0];
    const int* ei     = (const int*)d_in[1];
    const float* W1a  = (const float*)d_in[3];
    const float* b1a  = (const float*)d_in[4];
    const float* W1b  = (const float*)d_in[5];
    const float* b1b  = (const float*)d_in[6];
    const float* W2a  = (const float*)d_in[7];
    const float* b2a  = (const float*)d_in[8];
    const float* W2b  = (const float*)d_in[9];
    const float* b2b  = (const float*)d_in[10];
    const float* bn_g = (const float*)d_in[11];
    const float* bn_b = (const float*)d_in[12];
    const float* Wl   = (const float*)d_in[13];
    const float* Wr   = (const float*)d_in[14];
    const float* att  = (const float*)d_in[15];
    const float* gatb = (const float*)d_in[16];
    const float* ln_g = (const float*)d_in[17];
    const float* ln_b = (const float*)d_in[18];
    const float* Wp   = (const float*)d_in[19];
    const float* bp   = (const float*)d_in[20];

    const int* src = ei;
    const int* dst = ei + EE;

    float* out = (float*)d_out;
    float* out_pred = out;
    float* out_node = out + 1;
    float* out_edge = out + 1 + NN;

    // ---- workspace layout ----
    unsigned short* B0 = (unsigned short*)d_ws;
    unsigned short* B1 = B0 + (size_t)NN * 512;
    unsigned short* B2 = B1 + (size_t)NN * 512;
    unsigned short* B3 = B2 + (size_t)NN * 512;
    float* hbuf = (float*)B0;  // N*256 fp32 == N*512 bf16 bytes
    unsigned short* xl = B1;
    unsigned short* xr = B3;
    float* gout = (float*)B0;

    unsigned short* W1at = B3 + (size_t)NN * 512;
    unsigned short* W1bt = W1at + 512 * 512;
    unsigned short* W2at = W1bt + 512 * 512;
    unsigned short* W2bt = W2at + 256 * 512;
    unsigned short* Wlt  = W2bt + 256 * 256;
    unsigned short* Wrt  = Wlt + 256 * 256;
    float* alpha = (float*)(Wrt + 256 * 256);  // E*4 fp32, 16B-aligned
    float* na    = alpha + (size_t)EE * 4;     // 4*N
    float* csum  = na + 4 * NN;                // 256
    float* csq_  = csum + 256;                 // 256
    float* hm    = csq_ + 256;                 // 4
    float* hs    = hm + 4;                     // 4
    float* part  = hs + 4;                     // 5*512
    int* deg_in     = (int*)(part + 5 * 512);  // N
    int* deg_tot    = deg_in + NN;             // N
    int* row_start  = deg_tot + NN;            // N+1
    int* row_start2 = row_start + NN + 1;      // N+1
    int* cursor     = row_start2 + NN + 1;     // N
    int* cursor2    = cursor + NN;             // N
    int* csr        = cursor2 + NN;            // E
    int* adj2       = csr + EE;                // 2E

    hipMemsetAsync(csum, 0, (size_t)(256 + 256 + 4 + 4) * sizeof(float), stream);
    hipMemsetAsync(deg_in, 0, (size_t)(6 * NN + 2) * sizeof(int), stream);

    const int EB = (EE + 255) / 256;

    // weight prep (bf16, transposed to [N][K])
    wtrans_kernel<<<dim3(16, 16), 256, 0, stream>>>(W1a, W1at, 512, 512);
    wtrans_kernel<<<dim3(16, 16), 256, 0, stream>>>(W1b, W1bt, 512, 512);
    wtrans_kernel<<<dim3(8, 16), 256, 0, stream>>>(W2a, W2at, 512, 256);
    wtrans_kernel<<<dim3(8, 8), 256, 0, stream>>>(W2b, W2bt, 256, 256);
    wtrans_kernel<<<dim3(8, 8), 256, 0, stream>>>(Wl, Wlt, 256, 256);
    wtrans_kernel<<<dim3(8, 8), 256, 0, stream>>>(Wr, Wrt, 256, 256);

    cast_bf_kernel<<<(NN * 512 / 4 + 255) / 256, 256, 0, stream>>>(x, B0, NN * 512 / 4);

    deg_kernel<<<EB, 256, 0, stream>>>(src, dst, deg_in, deg_tot);
    scan2_kernel<<<2, 1024, 0, stream>>>(deg_in, row_start, deg_tot, row_start2, NN);
    fill_csr_kernel<<<EB, 256, 0, stream>>>(dst, row_start, cursor, csr);
    fill_adj2_kernel<<<EB, 256, 0, stream>>>(src, dst, row_start2, cursor2, adj2);

    // GIN layer 1
    agg_add_bf_kernel<<<NN, 256, 0, stream>>>(B0, B1, csr, row_start, src);  // z1
    gemm_mfma_kernel<1, 1><<<dim3(4, 157), 256, 0, stream>>>(B1, W1at, b1a, B2, NN, 512, 512);
    gemm_mfma_kernel<1, 1><<<dim3(4, 157), 256, 0, stream>>>(B2, W1bt, b1b, B3, NN, 512, 512);
    // GIN layer 2
    agg_add_bf_kernel<<<NN, 256, 0, stream>>>(B3, B0, csr, row_start, src);  // z2
    gemm_mfma_kernel<1, 1><<<dim3(2, 157), 256, 0, stream>>>(B0, W2at, b2a, B1, NN, 512, 256);
    gemm_mfma_kernel<0, 0><<<dim3(2, 157), 256, 0, stream>>>(B1, W2bt, b2b, hbuf, NN, 256, 256);

    // BatchNorm -> bf16 h_bn in B2
    bn_stats_kernel<<<200, 256, 0, stream>>>(hbuf, csum, csq_);
    bn_apply_bf_kernel<<<(NN * 256 + 255) / 256, 256, 0, stream>>>(hbuf, csum, csq_, bn_g, bn_b,
                                                                   B2);

    // GATv2 projections (bf16 out)
    gemm_mfma_kernel<0, 1><<<dim3(2, 157), 256, 0, stream>>>(B2, Wlt, nullptr, xl, NN, 256, 256);
    gemm_mfma_kernel<0, 1><<<dim3(2, 157), 256, 0, stream>>>(B2, Wrt, nullptr, xr, NN, 256, 256);

    // fused GATv2 edge phase: logits + softmax + PV + alpha
    gat_fused_kernel<<<(NN + 3) / 4, 256, 0, stream>>>(xl, xr, csr, row_start, src, att, gatb,
                                                       alpha, gout);

    node_att_gather_kernel<<<NN / 4, 256, 0, stream>>>(alpha, adj2, row_start2, na);
    edge_mean_kernel<<<EB, 256, 0, stream>>>(alpha, out_edge);
    head_stats_kernel<<<4, 1024, 0, stream>>>(na, deg_tot, hm, hs);
    node_out_kernel<<<(NN + 255) / 256, 256, 0, stream>>>(na, deg_tot, hm, hs, out_node);

    // fused LayerNorm + projection head (no same-address atomics)
    ln_fused_kernel<<<512, 256, 0, stream>>>(gout, ln_g, ln_b, Wp, part);
    ln_final_kernel<<<1, 512, 0, stream>>>(part, bp, out_pred);
}

// Round 12
// 643.889 us; speedup vs baseline: 2.6807x; 1.0921x over previous
//
#include <hip/hip_runtime.h>
#include <hip/hip_bf16.h>

#define NN 20000
#define TT 512
#define LL 256
#define HH 4
#define DD 64
#define EE 320000

typedef __attribute__((ext_vector_type(8))) short short8;
typedef __attribute__((ext_vector_type(4))) float f32x4;

__device__ __forceinline__ float bf2f(unsigned short u) {
    return __uint_as_float((unsigned)u << 16);
}
__device__ __forceinline__ unsigned short f2bf(float f) {
    __hip_bfloat16 h = __float2bfloat16(f);
    unsigned short r;
    __builtin_memcpy(&r, &h, 2);
    return r;
}
__device__ __forceinline__ void acc2(float& a0, float& a1, unsigned int u) {
    a0 += __uint_as_float(u << 16);
    a1 += __uint_as_float(u & 0xffff0000u);
}
__device__ __forceinline__ unsigned int pack2(float a0, float a1) {
    return (unsigned int)f2bf(a0) | ((unsigned int)f2bf(a1) << 16);
}

// ---------------- degree ----------------
__global__ void deg_kernel(const int* __restrict__ src, const int* __restrict__ dst,
                           int* deg_in, int* deg_tot) {
    int e = blockIdx.x * blockDim.x + threadIdx.x;
    if (e >= EE) return;
    atomicAdd(&deg_in[dst[e]], 1);
    atomicAdd(&deg_tot[src[e]], 1);
    atomicAdd(&deg_tot[dst[e]], 1);
}

// ---------------- parallel exclusive scan of deg_in & deg_tot (3 phases) ----------------
#define SCHUNKS 20  // ceil(20000/1024)
__global__ void scan_partial_kernel(const int* __restrict__ deg0, const int* __restrict__ deg1,
                                    int* __restrict__ psum) {
    __shared__ int red[4];
    int j = blockIdx.x;               // 0..39
    const int* deg = (j < SCHUNKS) ? deg0 : deg1;
    int c = (j < SCHUNKS) ? j : j - SCHUNKS;
    int base = c * 1024;
    int s = 0;
#pragma unroll
    for (int t = 0; t < 4; ++t) {
        int i = base + threadIdx.x + t * 256;
        if (i < NN) s += deg[i];
    }
#pragma unroll
    for (int o = 32; o > 0; o >>= 1) s += __shfl_xor(s, o);
    int lane = threadIdx.x & 63, wv = threadIdx.x >> 6;
    if (lane == 0) red[wv] = s;
    __syncthreads();
    if (threadIdx.x == 0) psum[j] = red[0] + red[1] + red[2] + red[3];
}

__global__ void scan_offsets_kernel(const int* __restrict__ psum, int* __restrict__ coff,
                                    int* rs0, int* rs1) {
    int a = threadIdx.x;  // 2 threads
    if (a >= 2) return;
    int run = 0;
    for (int c = 0; c < SCHUNKS; ++c) {
        coff[a * SCHUNKS + c] = run;
        run += psum[a * SCHUNKS + c];
    }
    if (a == 0) rs0[NN] = run;
    else rs1[NN] = run;
}

__global__ void scan_apply_kernel(const int* __restrict__ deg0, const int* __restrict__ deg1,
                                  const int* __restrict__ coff, int* __restrict__ rs0,
                                  int* __restrict__ rs1) {
    __shared__ int sm[1024];
    int j = blockIdx.x;
    const int* deg = (j < SCHUNKS) ? deg0 : deg1;
    int* rs = (j < SCHUNKS) ? rs0 : rs1;
    int c = (j < SCHUNKS) ? j : j - SCHUNKS;
    int tid = threadIdx.x;
    int i = c * 1024 + tid;
    int v = (i < NN) ? deg[i] : 0;
    sm[tid] = v;
    __syncthreads();
    for (int off = 1; off < 1024; off <<= 1) {
        int t = (tid >= off) ? sm[tid - off] : 0;
        __syncthreads();
        sm[tid] += t;
        __syncthreads();
    }
    if (i < NN) rs[i] = coff[j] + sm[tid] - v;
}

__global__ void fill_csr_kernel(const int* __restrict__ dst, const int* __restrict__ row_start,
                                int* cursor, int* csr) {
    int e = blockIdx.x * blockDim.x + threadIdx.x;
    if (e >= EE) return;
    int d = dst[e];
    int p = atomicAdd(&cursor[d], 1);
    csr[row_start[d] + p] = e;
}

__global__ void fill_adj2_kernel(const int* __restrict__ src, const int* __restrict__ dst,
                                 const int* __restrict__ rs2, int* cursor2, int* adj2) {
    int e = blockIdx.x * blockDim.x + threadIdx.x;
    if (e >= EE) return;
    int s = src[e];
    int p = atomicAdd(&cursor2[s], 1);
    adj2[rs2[s] + p] = e;
    int t = dst[e];
    int q = atomicAdd(&cursor2[t], 1);
    adj2[rs2[t] + q] = e;
}

// ---------------- cast fp32 -> bf16 ----------------
__global__ void cast_bf_kernel(const float* __restrict__ in, unsigned short* __restrict__ out,
                               int n4) {
    int i = blockIdx.x * blockDim.x + threadIdx.x;
    if (i >= n4) return;
    float4 v = ((const float4*)in)[i];
    ushort4 o;
    o.x = f2bf(v.x); o.y = f2bf(v.y); o.z = f2bf(v.z); o.w = f2bf(v.w);
    ((ushort4*)out)[i] = o;
}

// ---------------- all 6 weight transposes in one dispatch ----------------
__global__ void wtrans_all_kernel(const float* __restrict__ W1a, const float* __restrict__ W1b,
                                  const float* __restrict__ W2a, const float* __restrict__ W2b,
                                  const float* __restrict__ Wl, const float* __restrict__ Wr,
                                  unsigned short* W1at, unsigned short* W1bt,
                                  unsigned short* W2at, unsigned short* W2bt,
                                  unsigned short* Wlt, unsigned short* Wrt) {
    __shared__ float t[32][33];
    int j = blockIdx.x;
    const float* W; unsigned short* Wt; int K, N, tx;
    if (j < 256)      { W = W1a; Wt = W1at; K = 512; N = 512; tx = 16; }
    else if (j < 512) { W = W1b; Wt = W1bt; K = 512; N = 512; tx = 16; j -= 256; }
    else if (j < 640) { W = W2a; Wt = W2at; K = 512; N = 256; tx = 8;  j -= 512; }
    else if (j < 704) { W = W2b; Wt = W2bt; K = 256; N = 256; tx = 8;  j -= 640; }
    else if (j < 768) { W = Wl;  Wt = Wlt;  K = 256; N = 256; tx = 8;  j -= 704; }
    else              { W = Wr;  Wt = Wrt;  K = 256; N = 256; tx = 8;  j -= 768; }
    int bn = (j % tx) * 32, bk = (j / tx) * 32;
    int x = threadIdx.x & 31, y = threadIdx.x >> 5;
#pragma unroll
    for (int i = 0; i < 32; i += 8) t[y + i][x] = W[(size_t)(bk + y + i) * N + bn + x];
    __syncthreads();
#pragma unroll
    for (int i = 0; i < 32; i += 8)
        Wt[(size_t)(bn + y + i) * K + bk + x] = f2bf(t[x][y + i]);
}

// ---------------- wave-per-node aggregation: Z = X + segsum(X[src]->dst) ----------------
// ELEMS = row_width/64 (8 -> 512 wide, 4 -> 256 wide). BIAS_RELU: Z = relu(Z + bias).
template <int ELEMS, int BIAS_RELU>
__global__ void agg_wave_kernel(const unsigned short* __restrict__ X,
                                unsigned short* __restrict__ Z,
                                const int* __restrict__ csr, const int* __restrict__ rs,
                                const int* __restrict__ src, const float* __restrict__ bias) {
    const int lane = threadIdx.x & 63;
    const int wave = threadIdx.x >> 6;
    const int node = blockIdx.x * 4 + wave;
    if (node >= NN) return;
    const int F = ELEMS * 64;
    const int start = rs[node], end = rs[node + 1];
    float a[ELEMS];
    if constexpr (ELEMS == 8) {
        uint4 u = ((const uint4*)(X + (size_t)node * F))[lane];
        a[0] = __uint_as_float(u.x << 16); a[1] = __uint_as_float(u.x & 0xffff0000u);
        a[2] = __uint_as_float(u.y << 16); a[3] = __uint_as_float(u.y & 0xffff0000u);
        a[4] = __uint_as_float(u.z << 16); a[5] = __uint_as_float(u.z & 0xffff0000u);
        a[6] = __uint_as_float(u.w << 16); a[7] = __uint_as_float(u.w & 0xffff0000u);
    } else {
        uint2 u = ((const uint2*)(X + (size_t)node * F))[lane];
        a[0] = __uint_as_float(u.x << 16); a[1] = __uint_as_float(u.x & 0xffff0000u);
        a[2] = __uint_as_float(u.y << 16); a[3] = __uint_as_float(u.y & 0xffff0000u);
    }
    for (int base = start; base < end; base += 64) {
        const int cnt = min(64, end - base);
        int e = (lane < cnt) ? csr[base + lane] : 0;
        int sid = (lane < cnt) ? src[e] : 0;
        for (int i = 0; i < cnt; ++i) {
            const int s = __shfl(sid, i);
            if constexpr (ELEMS == 8) {
                uint4 u = ((const uint4*)(X + (size_t)s * F))[lane];
                acc2(a[0], a[1], u.x); acc2(a[2], a[3], u.y);
                acc2(a[4], a[5], u.z); acc2(a[6], a[7], u.w);
            } else {
                uint2 u = ((const uint2*)(X + (size_t)s * F))[lane];
                acc2(a[0], a[1], u.x); acc2(a[2], a[3], u.y);
            }
        }
    }
    if (BIAS_RELU) {
#pragma unroll
        for (int j = 0; j < ELEMS; ++j) a[j] = fmaxf(a[j] + bias[lane * ELEMS + j], 0.f);
    }
    if constexpr (ELEMS == 8) {
        uint4 o;
        o.x = pack2(a[0], a[1]); o.y = pack2(a[2], a[3]);
        o.z = pack2(a[4], a[5]); o.w = pack2(a[6], a[7]);
        ((uint4*)(Z + (size_t)node * F))[lane] = o;
    } else {
        uint2 o;
        o.x = pack2(a[0], a[1]); o.y = pack2(a[2], a[3]);
        ((uint2*)(Z + (size_t)node * F))[lane] = o;
    }
}

// ---------------- bf16 MFMA GEMM: C = [relu](A[M,K] @ Bt[N,K]^T + bias) ----------------
template <int RELU, int OUT_BF16>
__global__ __launch_bounds__(256)
void gemm_mfma_kernel(const unsigned short* __restrict__ A,
                      const unsigned short* __restrict__ Bt,
                      const float* __restrict__ bias, void* __restrict__ Cout,
                      int M, int K, int Nn) {
    __shared__ unsigned short lds[2][2][4][128][8];  // 32 KiB
    const int tid = threadIdx.x;
    const int wid = tid >> 6, lane = tid & 63;
    const int brow = blockIdx.y * 128, bcol = blockIdx.x * 128;
    const int wr = wid >> 1, wc = wid & 1;
    const int khi = lane >> 4, r15 = lane & 15;

    f32x4 acc[4][4] = {};

    const int q0 = wid * 2, q1 = wid * 2 + 1;
    const int kh0 = q0 >> 1, rh0 = q0 & 1;
    const int kh1 = q1 >> 1, rh1 = q1 & 1;
    int ar0 = brow + rh0 * 64 + lane; ar0 = ar0 < M ? ar0 : M - 1;
    int ar1 = brow + rh1 * 64 + lane; ar1 = ar1 < M ? ar1 : M - 1;
    const int bc0 = bcol + rh0 * 64 + lane;
    const int bc1 = bcol + rh1 * 64 + lane;
    const unsigned short* gA0 = A + (size_t)ar0 * K + kh0 * 8;
    const unsigned short* gA1 = A + (size_t)ar1 * K + kh1 * 8;
    const unsigned short* gB0 = Bt + (size_t)bc0 * K + kh0 * 8;
    const unsigned short* gB1 = Bt + (size_t)bc1 * K + kh1 * 8;

#define GLL(gp, lp) __builtin_amdgcn_global_load_lds( \
        (const __attribute__((address_space(1))) unsigned int*)(gp), \
        (__attribute__((address_space(3))) unsigned int*)(lp), 16, 0, 0)
#define STAGE(buf, kt) do { const int koff = (kt) * 32; \
        GLL(gA0 + koff, &lds[buf][0][kh0][rh0 * 64][0]); \
        GLL(gA1 + koff, &lds[buf][0][kh1][rh1 * 64][0]); \
        GLL(gB0 + koff, &lds[buf][1][kh0][rh0 * 64][0]); \
        GLL(gB1 + koff, &lds[buf][1][kh1][rh1 * 64][0]); \
    } while (0)

    const int NT = K >> 5;
    STAGE(0, 0);
    for (int kt = 0; kt < NT; ++kt) {
        const int cur = kt & 1;
        __syncthreads();
        if (kt + 1 < NT) STAGE(cur ^ 1, kt + 1);
        short8 af[4], bfv[4];
#pragma unroll
        for (int m = 0; m < 4; ++m)
            af[m] = *(const short8*)&lds[cur][0][khi][wr * 64 + m * 16 + r15][0];
#pragma unroll
        for (int n = 0; n < 4; ++n)
            bfv[n] = *(const short8*)&lds[cur][1][khi][wc * 64 + n * 16 + r15][0];
#pragma unroll
        for (int m = 0; m < 4; ++m)
#pragma unroll
            for (int n = 0; n < 4; ++n)
                acc[m][n] =
                    __builtin_amdgcn_mfma_f32_16x16x32_bf16(af[m], bfv[n], acc[m][n], 0, 0, 0);
    }
#undef STAGE
#undef GLL

#pragma unroll
    for (int m = 0; m < 4; ++m) {
#pragma unroll
        for (int n = 0; n < 4; ++n) {
            const int col = bcol + wc * 64 + n * 16 + r15;
            const float bb = bias ? bias[col] : 0.f;
            f32x4 v = acc[m][n];
#pragma unroll
            for (int r = 0; r < 4; ++r) {
                const int row = brow + wr * 64 + m * 16 + khi * 4 + r;
                if (row < M) {
                    float o = v[r] + bb;
                    if (RELU) o = fmaxf(o, 0.f);
                    if (OUT_BF16)
                        ((unsigned short*)Cout)[(size_t)row * Nn + col] = f2bf(o);
                    else
                        ((float*)Cout)[(size_t)row * Nn + col] = o;
                }
            }
        }
    }
}

// ---------------- BatchNorm ----------------
__global__ void bn_stats_kernel(const float* __restrict__ h, float* cs, float* csq) {
    int col = threadIdx.x;  // 256
    int r0 = blockIdx.x * 100;
    int r1 = min(r0 + 100, NN);
    float s = 0.f, sq = 0.f;
    for (int r = r0; r < r1; r++) {
        float v = h[(size_t)r * 256 + col];
        s += v;
        sq += v * v;
    }
    atomicAdd(&cs[col], s);
    atomicAdd(&csq[col], sq);
}

__global__ void bn_apply_bf_kernel(const float* __restrict__ h, const float* __restrict__ cs,
                                   const float* __restrict__ csq, const float* __restrict__ g,
                                   const float* __restrict__ b, unsigned short* __restrict__ out) {
    int i = blockIdx.x * blockDim.x + threadIdx.x;
    if (i >= NN * 256) return;
    int col = i & 255;
    float mu = cs[col] * (1.f / NN);
    float var = csq[col] * (1.f / NN) - mu * mu;
    float inv = rsqrtf(var + 1e-5f);
    out[i] = f2bf((h[i] - mu) * inv * g[col] + b[col]);
}

// ---------------- FUSED GATv2 ----------------
__global__ void gat_fused_kernel(const unsigned short* __restrict__ xl,
                                 const unsigned short* __restrict__ xr,
                                 const int* __restrict__ csr, const int* __restrict__ rs,
                                 const int* __restrict__ src, const float* __restrict__ att,
                                 const float* __restrict__ gatb,
                                 float* __restrict__ alpha, float* __restrict__ out) {
    const int lane = threadIdx.x & 63;
    const int wave = threadIdx.x >> 6;
    const int node = blockIdx.x * 4 + wave;
    if (node >= NN) return;
    const int start = rs[node], end = rs[node + 1];
    const int deg = end - start;
    const int h = lane >> 4;
    const int l15 = lane & 15;

    const float4 attv = ((const float4*)att)[lane];
    const uint2 uxr = ((const uint2*)(xr + (size_t)node * 256))[lane];
    const float xr0 = bf2f((unsigned short)(uxr.x & 0xffff));
    const float xr1 = bf2f((unsigned short)(uxr.x >> 16));
    const float xr2 = bf2f((unsigned short)(uxr.y & 0xffff));
    const float xr3 = bf2f((unsigned short)(uxr.y >> 16));

    float m = -1e30f, S = 0.f;
    float O0 = 0.f, O1 = 0.f, O2 = 0.f, O3 = 0.f;
    float lg0 = 0.f, lg1 = 0.f, lg2 = 0.f, lg3 = 0.f;
    const bool fast = (deg <= 64);
    int eid = 0;

    for (int base = start; base < end; base += 64) {
        const int cnt = min(64, end - base);
        eid = (lane < cnt) ? csr[base + lane] : 0;
        int sid = (lane < cnt) ? src[eid] : 0;
        for (int i = 0; i < cnt; ++i) {
            const int s = __shfl(sid, i);
            const uint2 u = ((const uint2*)(xl + (size_t)s * 256))[lane];
            const float x0 = bf2f((unsigned short)(u.x & 0xffff));
            const float x1 = bf2f((unsigned short)(u.x >> 16));
            const float x2 = bf2f((unsigned short)(u.y & 0xffff));
            const float x3 = bf2f((unsigned short)(u.y >> 16));
            float a0 = x0 + xr0; a0 = a0 > 0.f ? a0 : 0.2f * a0;
            float a1 = x1 + xr1; a1 = a1 > 0.f ? a1 : 0.2f * a1;
            float a2 = x2 + xr2; a2 = a2 > 0.f ? a2 : 0.2f * a2;
            float a3 = x3 + xr3; a3 = a3 > 0.f ? a3 : 0.2f * a3;
            float p = a0 * attv.x + a1 * attv.y + a2 * attv.z + a3 * attv.w;
#pragma unroll
            for (int o = 1; o < 16; o <<= 1) p += __shfl_xor(p, o);
            if (fast && l15 == (i & 15)) {
                const int t = i >> 4;
                if (t == 0) lg0 = p;
                else if (t == 1) lg1 = p;
                else if (t == 2) lg2 = p;
                else lg3 = p;
            }
            const float mn = fmaxf(m, p);
            const float sc = __expf(m - mn);
            const float w = __expf(p - mn);
            S = S * sc + w;
            O0 = O0 * sc + w * x0;
            O1 = O1 * sc + w * x1;
            O2 = O2 * sc + w * x2;
            O3 = O3 * sc + w * x3;
            m = mn;
        }
    }

    const float rS = (deg > 0) ? 1.f / S : 0.f;
    const float4 bv = ((const float4*)gatb)[lane];
    float4 ov;
    ov.x = O0 * rS + bv.x; ov.y = O1 * rS + bv.y;
    ov.z = O2 * rS + bv.z; ov.w = O3 * rS + bv.w;
    ((float4*)(out + (size_t)node * 256))[lane] = ov;

    if (deg == 0) return;
    if (fast) {
#pragma unroll
        for (int t = 0; t < 4; ++t) {
            const int k = l15 + t * 16;
            if (k < deg) {
                const int e = __shfl(eid, k);
                const float l = (t == 0) ? lg0 : (t == 1) ? lg1 : (t == 2) ? lg2 : lg3;
                alpha[(size_t)e * 4 + h] = __expf(l - m) * rS;
            }
        }
    } else {
        for (int base = start; base < end; base += 64) {
            const int cnt = min(64, end - base);
            const int eid2 = (lane < cnt) ? csr[base + lane] : 0;
            const int sid2 = (lane < cnt) ? src[eid2] : 0;
            for (int i = 0; i < cnt; ++i) {
                const int s = __shfl(sid2, i);
                const uint2 u = ((const uint2*)(xl + (size_t)s * 256))[lane];
                float a0 = bf2f((unsigned short)(u.x & 0xffff)) + xr0; a0 = a0 > 0.f ? a0 : 0.2f * a0;
                float a1 = bf2f((unsigned short)(u.x >> 16)) + xr1;    a1 = a1 > 0.f ? a1 : 0.2f * a1;
                float a2 = bf2f((unsigned short)(u.y & 0xffff)) + xr2; a2 = a2 > 0.f ? a2 : 0.2f * a2;
                float a3 = bf2f((unsigned short)(u.y >> 16)) + xr3;    a3 = a3 > 0.f ? a3 : 0.2f * a3;
                float p = a0 * attv.x + a1 * attv.y + a2 * attv.z + a3 * attv.w;
#pragma unroll
                for (int o = 1; o < 16; o <<= 1) p += __shfl_xor(p, o);
                const int e = __shfl(eid2, i);
                if (l15 == 0) alpha[(size_t)e * 4 + h] = __expf(p - m) * rS;
            }
        }
    }
}

// ---------------- node_att via combined-CSR gather ----------------
__global__ void node_att_gather_kernel(const float* __restrict__ abuf,
                                       const int* __restrict__ adj2,
                                       const int* __restrict__ rs2, float* __restrict__ na) {
    int lane = threadIdx.x & 63;
    int wave = threadIdx.x >> 6;
    int node = blockIdx.x * 4 + wave;
    if (node >= NN) return;
    int start = rs2[node], end = rs2[node + 1];
    float s0 = 0.f, s1 = 0.f, s2 = 0.f, s3 = 0.f;
    for (int k = start + lane; k < end; k += 64) {
        int e = adj2[k];
        s0 += abuf[e];
        s1 += abuf[EE + e];
        s2 += abuf[2 * EE + e];
        s3 += abuf[3 * EE + e];
    }
#pragma unroll
    for (int o = 32; o > 0; o >>= 1) {
        s0 += __shfl_xor(s0, o);
        s1 += __shfl_xor(s1, o);
        s2 += __shfl_xor(s2, o);
        s3 += __shfl_xor(s3, o);
    }
    if (lane == 0) {
        na[node] = s0;
        na[NN + node] = s1;
        na[2 * NN + node] = s2;
        na[3 * NN + node] = s3;
    }
}

__global__ void edge_mean_kernel(const float* __restrict__ abuf, float* __restrict__ out_edge) {
    int e = blockIdx.x * blockDim.x + threadIdx.x;
    if (e >= EE) return;
    out_edge[e] = 0.25f * (abuf[e] + abuf[EE + e] + abuf[2 * EE + e] + abuf[3 * EE + e]);
}

__global__ void head_stats_kernel(const float* __restrict__ na, const int* __restrict__ deg_tot,
                                  float* hm, float* hs) {
    __shared__ float red[1024];
    int h = blockIdx.x;
    int tid = threadIdx.x;
    float m = -1e30f;
    for (int i = tid; i < NN; i += 1024) {
        float v = na[h * NN + i] / ((float)deg_tot[i] + 1e-9f);
        m = fmaxf(m, v);
    }
    red[tid] = m;
    __syncthreads();
    for (int o = 512; o > 0; o >>= 1) {
        if (tid < o) red[tid] = fmaxf(red[tid], red[tid + o]);
        __syncthreads();
    }
    m = red[0];
    __syncthreads();
    float s = 0.f;
    for (int i = tid; i < NN; i += 1024) {
        float v = na[h * NN + i] / ((float)deg_tot[i] + 1e-9f);
        s += __expf(v - m);
    }
    red[tid] = s;
    __syncthreads();
    for (int o = 512; o > 0; o >>= 1) {
        if (tid < o) red[tid] += red[tid + o];
        __syncthreads();
    }
    if (tid == 0) {
        hm[h] = m;
        hs[h] = red[0];
    }
}

__global__ void node_out_kernel(const float* __restrict__ na, const int* __restrict__ deg_tot,
                                const float* __restrict__ hm, const float* __restrict__ hs,
                                float* __restrict__ out_node) {
    int i = blockIdx.x * blockDim.x + threadIdx.x;
    if (i >= NN) return;
    float acc = 0.f;
#pragma unroll
    for (int h = 0; h < 4; h++) {
        float v = na[h * NN + i] / ((float)deg_tot[i] + 1e-9f);
        acc += __expf(v - hm[h]) / hs[h];
    }
    out_node[i] = 0.25f * acc;
}

// ---------------- fused LayerNorm(N*L)+Linear ----------------
__global__ void ln_fused_kernel(const float* __restrict__ x, const float* __restrict__ g,
                                const float* __restrict__ b, const float* __restrict__ Wp,
                                float* __restrict__ part) {
    const int total4 = NN * 64;
    const float4* x4 = (const float4*)x;
    const float4* g4 = (const float4*)g;
    const float4* b4 = (const float4*)b;
    const float4* w4 = (const float4*)Wp;
    float s1 = 0.f, s2 = 0.f, s3 = 0.f, s4 = 0.f, s5 = 0.f;
    for (int i = blockIdx.x * blockDim.x + threadIdx.x; i < total4;
         i += gridDim.x * blockDim.x) {
        float4 xv = x4[i], gv = g4[i], bv = b4[i], wv = w4[i];
        s1 += xv.x + xv.y + xv.z + xv.w;
        s2 += xv.x * xv.x + xv.y * xv.y + xv.z * xv.z + xv.w * xv.w;
        float gw0 = gv.x * wv.x, gw1 = gv.y * wv.y, gw2 = gv.z * wv.z, gw3 = gv.w * wv.w;
        s3 += xv.x * gw0 + xv.y * gw1 + xv.z * gw2 + xv.w * gw3;
        s4 += gw0 + gw1 + gw2 + gw3;
        s5 += bv.x * wv.x + bv.y * wv.y + bv.z * wv.z + bv.w * wv.w;
    }
#pragma unroll
    for (int o = 32; o > 0; o >>= 1) {
        s1 += __shfl_xor(s1, o);
        s2 += __shfl_xor(s2, o);
        s3 += __shfl_xor(s3, o);
        s4 += __shfl_xor(s4, o);
        s5 += __shfl_xor(s5, o);
    }
    __shared__ float sm[4][5];
    int lane = threadIdx.x & 63, wv_ = threadIdx.x >> 6;
    if (lane == 0) {
        sm[wv_][0] = s1; sm[wv_][1] = s2; sm[wv_][2] = s3; sm[wv_][3] = s4; sm[wv_][4] = s5;
    }
    __syncthreads();
    if (threadIdx.x == 0) {
        float t1 = 0.f, t2 = 0.f, t3 = 0.f, t4 = 0.f, t5 = 0.f;
#pragma unroll
        for (int w = 0; w < 4; ++w) {
            t1 += sm[w][0]; t2 += sm[w][1]; t3 += sm[w][2]; t4 += sm[w][3]; t5 += sm[w][4];
        }
        part[0 * 512 + blockIdx.x] = t1;
        part[1 * 512 + blockIdx.x] = t2;
        part[2 * 512 + blockIdx.x] = t3;
        part[3 * 512 + blockIdx.x] = t4;
        part[4 * 512 + blockIdx.x] = t5;
    }
}

__global__ void ln_final_kernel(const float* __restrict__ part, const float* __restrict__ bp,
                                float* __restrict__ out) {
    float v0 = part[0 * 512 + threadIdx.x];
    float v1 = part[1 * 512 + threadIdx.x];
    float v2 = part[2 * 512 + threadIdx.x];
    float v3 = part[3 * 512 + threadIdx.x];
    float v4 = part[4 * 512 + threadIdx.x];
#pragma unroll
    for (int o = 32; o > 0; o >>= 1) {
        v0 += __shfl_xor(v0, o);
        v1 += __shfl_xor(v1, o);
        v2 += __shfl_xor(v2, o);
        v3 += __shfl_xor(v3, o);
        v4 += __shfl_xor(v4, o);
    }
    __shared__ float sm[8][5];
    int lane = threadIdx.x & 63, wv_ = threadIdx.x >> 6;
    if (lane == 0) {
        sm[wv_][0] = v0; sm[wv_][1] = v1; sm[wv_][2] = v2; sm[wv_][3] = v3; sm[wv_][4] = v4;
    }
    __syncthreads();
    if (threadIdx.x == 0) {
        float S1 = 0.f, S2 = 0.f, S3 = 0.f, S4 = 0.f, S5 = 0.f;
#pragma unroll
        for (int w = 0; w < 8; ++w) {
            S1 += sm[w][0]; S2 += sm[w][1]; S3 += sm[w][2]; S4 += sm[w][3]; S5 += sm[w][4];
        }
        const float M = (float)NN * 256.f;
        float mu = S1 / M;
        float var = S2 / M - mu * mu;
        float inv = rsqrtf(var + 1e-5f);
        float z = inv * (S3 - mu * S4) + S5 + bp[0];
        out[0] = 1.f / (1.f + __expf(-z));
    }
}

extern "C" void kernel_launch(void* const* d_in, const int* in_sizes, int n_in,
                              void* d_out, int out_size, void* d_ws, size_t ws_size,
                              hipStream_t stream) {
    const float* x    = (const float*)d_in[0];
    const int* ei     = (const int*)d_in[1];
    const float* W1a  = (const float*)d_in[3];
    const float* b1a  = (const float*)d_in[4];
    const float* W1b  = (const float*)d_in[5];
    const float* b1b  = (const float*)d_in[6];
    const float* W2a  = (const float*)d_in[7];
    const float* b2a  = (const float*)d_in[8];
    const float* W2b  = (const float*)d_in[9];
    const float* b2b  = (const float*)d_in[10];
    const float* bn_g = (const float*)d_in[11];
    const float* bn_b = (const float*)d_in[12];
    const float* Wl   = (const float*)d_in[13];
    const float* Wr   = (const float*)d_in[14];
    const float* att  = (const float*)d_in[15];
    const float* gatb = (const float*)d_in[16];
    const float* ln_g = (const float*)d_in[17];
    const float* ln_b = (const float*)d_in[18];
    const float* Wp   = (const float*)d_in[19];
    const float* bp   = (const float*)d_in[20];

    const int* src = ei;
    const int* dst = ei + EE;

    float* out = (float*)d_out;
    float* out_pred = out;
    float* out_node = out + 1;
    float* out_edge = out + 1 + NN;

    // ---- workspace layout ----
    unsigned short* B0 = (unsigned short*)d_ws;
    unsigned short* B1 = B0 + (size_t)NN * 512;
    unsigned short* B2 = B1 + (size_t)NN * 512;
    unsigned short* B3 = B2 + (size_t)NN * 512;
    float* hbuf = (float*)B0;
    unsigned short* xl = B1;
    unsigned short* xr = B3;
    float* gout = (float*)B0;

    unsigned short* W1at = B3 + (size_t)NN * 512;
    unsigned short* W1bt = W1at + 512 * 512;
    unsigned short* W2at = W1bt + 512 * 512;
    unsigned short* W2bt = W2at + 256 * 512;
    unsigned short* Wlt  = W2bt + 256 * 256;
    unsigned short* Wrt  = Wlt + 256 * 256;
    float* alpha = (float*)(Wrt + 256 * 256);
    float* na    = alpha + (size_t)EE * 4;
    float* csum  = na + 4 * NN;
    float* csq_  = csum + 256;
    float* hm    = csq_ + 256;
    float* hs    = hm + 4;
    float* part  = hs + 4;                     // 5*512
    int* deg_in     = (int*)(part + 5 * 512);
    int* deg_tot    = deg_in + NN;
    int* row_start  = deg_tot + NN;            // N+1
    int* row_start2 = row_start + NN + 1;      // N+1
    int* cursor     = row_start2 + NN + 1;
    int* cursor2    = cursor + NN;
    int* csr        = cursor2 + NN;            // E
    int* adj2       = csr + EE;                // 2E
    int* psum       = adj2 + 2 * EE;           // 40
    int* coff       = psum + 40;               // 40

    hipMemsetAsync(csum, 0, (size_t)(256 + 256 + 4 + 4) * sizeof(float), stream);
    hipMemsetAsync(deg_in, 0, (size_t)(6 * NN + 2) * sizeof(int), stream);

    const int EB = (EE + 255) / 256;

    wtrans_all_kernel<<<832, 256, 0, stream>>>(W1a, W1b, W2a, W2b, Wl, Wr, W1at, W1bt, W2at,
                                               W2bt, Wlt, Wrt);
    cast_bf_kernel<<<(NN * 512 / 4 + 255) / 256, 256, 0, stream>>>(x, B0, NN * 512 / 4);

    deg_kernel<<<EB, 256, 0, stream>>>(src, dst, deg_in, deg_tot);
    scan_partial_kernel<<<2 * SCHUNKS, 256, 0, stream>>>(deg_in, deg_tot, psum);
    scan_offsets_kernel<<<1, 64, 0, stream>>>(psum, coff, row_start, row_start2);
    scan_apply_kernel<<<2 * SCHUNKS, 1024, 0, stream>>>(deg_in, deg_tot, coff, row_start,
                                                        row_start2);
    fill_csr_kernel<<<EB, 256, 0, stream>>>(dst, row_start, cursor, csr);
    fill_adj2_kernel<<<EB, 256, 0, stream>>>(src, dst, row_start2, cursor2, adj2);

    // GIN layer 1: z1 = x + agg(x); t1 = relu(z1@W1a+b1a); h1 = relu(t1@W1b+b1b)
    agg_wave_kernel<8, 0><<<NN / 4, 256, 0, stream>>>(B0, B1, csr, row_start, src, nullptr);
    gemm_mfma_kernel<1, 1><<<dim3(4, 157), 256, 0, stream>>>(B1, W1at, b1a, B2, NN, 512, 512);
    gemm_mfma_kernel<1, 1><<<dim3(4, 157), 256, 0, stream>>>(B2, W1bt, b1b, B3, NN, 512, 512);
    // GIN layer 2, agg-after-GEMM: y = h1@W2a; t2 = relu(y + agg(y) + b2a); h = t2@W2b + b2b
    gemm_mfma_kernel<0, 1><<<dim3(2, 157), 256, 0, stream>>>(B3, W2at, nullptr, B1, NN, 512, 256);
    agg_wave_kernel<4, 1><<<NN / 4, 256, 0, stream>>>(B1, B2, csr, row_start, src, b2a);
    gemm_mfma_kernel<0, 0><<<dim3(2, 157), 256, 0, stream>>>(B2, W2bt, b2b, hbuf, NN, 256, 256);

    // BatchNorm -> bf16 h_bn in B2
    bn_stats_kernel<<<200, 256, 0, stream>>>(hbuf, csum, csq_);
    bn_apply_bf_kernel<<<(NN * 256 + 255) / 256, 256, 0, stream>>>(hbuf, csum, csq_, bn_g, bn_b,
                                                                   B2);

    // GATv2 projections
    gemm_mfma_kernel<0, 1><<<dim3(2, 157), 256, 0, stream>>>(B2, Wlt, nullptr, xl, NN, 256, 256);
    gemm_mfma_kernel<0, 1><<<dim3(2, 157), 256, 0, stream>>>(B2, Wrt, nullptr, xr, NN, 256, 256);

    gat_fused_kernel<<<(NN + 3) / 4, 256, 0, stream>>>(xl, xr, csr, row_start, src, att, gatb,
                                                       alpha, gout);

    node_att_gather_kernel<<<NN / 4, 256, 0, stream>>>(alpha, adj2, row_start2, na);
    edge_mean_kernel<<<EB, 256, 0, stream>>>(alpha, out_edge);
    head_stats_kernel<<<4, 1024, 0, stream>>>(na, deg_tot, hm, hs);
    node_out_kernel<<<(NN + 255) / 256, 256, 0, stream>>>(na, deg_tot, hm, hs, out_node);

    ln_fused_kernel<<<512, 256, 0, stream>>>(gout, ln_g, ln_b, Wp, part);
    ln_final_kernel<<<1, 512, 0, stream>>>(part, bp, out_pred);
}